// Round 15
// baseline (891.964 us; speedup 1.0000x reference)
//
#include <hip/hip_runtime.h>
#include <hip/hip_bf16.h>
#include <math.h>

#define NHEAD 4
#define DH 128
#define HID 512
#define NLAY 2
#define NP 30000
#define NA 10000
#define INDIM 768
#define EC 150000
#define EW 80000
#define EB 80000
#define NQP 2560   // q | kv0 | kv2
#define NQA 1536   // q | kv1

typedef __hip_bfloat16 bf16;
typedef __attribute__((ext_vector_type(8))) short bf16x8;
typedef __attribute__((ext_vector_type(4))) float f32x4;
typedef __attribute__((ext_vector_type(4))) unsigned int u32x4;

__device__ __forceinline__ unsigned short f2bu(float f){ bf16 t = __float2bfloat16(f); return *(unsigned short*)&t; }
__device__ __forceinline__ float bu2f(unsigned short u){ return __uint_as_float((unsigned)u << 16); }

__device__ __forceinline__ void load8b(const bf16* __restrict__ p, int i8, float* o){
  uint4 r = ((const uint4*)p)[i8];
  o[0]=__uint_as_float(r.x<<16); o[1]=__uint_as_float(r.x&0xffff0000u);
  o[2]=__uint_as_float(r.y<<16); o[3]=__uint_as_float(r.y&0xffff0000u);
  o[4]=__uint_as_float(r.z<<16); o[5]=__uint_as_float(r.z&0xffff0000u);
  o[6]=__uint_as_float(r.w<<16); o[7]=__uint_as_float(r.w&0xffff0000u);
}

// async global->LDS, 16B per lane, wave-uniform LDS base + lane*16
__device__ __forceinline__ void gload16(const void* g, void* l) {
  __builtin_amdgcn_global_load_lds((const __attribute__((address_space(1))) void*)g,
                                   (__attribute__((address_space(3))) void*)l, 16, 0, 0);
}

// ---------------------------------------------------------------------------
// Paired MFMA bf16 GEMM: two sub-GEMMs in ONE launch. 128x128 tile, BK=64,
// single-buffered LDS; smem capped at EXACTLY 32KB -> 5 blocks/CU (was 33.8KB
// -> 4). bf16 C: TWO-HALF LDS-bounce epilogue (64x132 tile, 16.9KB, stays
// within the 32KB staging union) -> 16B/lane NT stores. fp32 C: direct NT.
// Inline per-iteration addressing (hoisting regressed, r13). XCD swizzle.
// ---------------------------------------------------------------------------
struct GemmPair {
  const bf16 *A0, *A1, *B0, *B1;
  const float *b0, *b1;
  void *C0, *C1;
  int lda0, lda1, ldb0, ldb1, ldc0, ldc1;
  int M0, M1, K0, K1;
  int act0, act1, bf0, bf1;      // bfX: 1 = bf16 C, 0 = fp32 C
  int nbn0, nbn1, nw0;
};

#define TSTRIDE 132   // padded bf16 epilogue stride (conflict-free deposit)

__global__ __launch_bounds__(256)
void mfma_gemm2(GemmPair gp)
{
  __shared__ __align__(16) short smem[16384];   // exactly 32 KB
  const int tid = threadIdx.x;
  const int lane = tid & 63, w = tid >> 6;
  const int nwg = gridDim.x;
  const int bid = blockIdx.x;
  const int xcd = bid & 7, pos = bid >> 3;
  const int q8 = nwg >> 3, r8 = nwg & 7;
  const int work = (xcd < r8 ? xcd * (q8 + 1) : r8 * (q8 + 1) + (xcd - r8) * q8) + pos;
  const int g = work >= gp.nw0;
  const int w2 = g ? work - gp.nw0 : work;
  const bf16* A  = g ? gp.A1 : gp.A0;
  const bf16* Bt = g ? gp.B1 : gp.B0;
  const float* bias = g ? gp.b1 : gp.b0;
  void* Cv = g ? gp.C1 : gp.C0;
  const int lda = g ? gp.lda1 : gp.lda0;
  const int ldb = g ? gp.ldb1 : gp.ldb0;
  const int ldc = g ? gp.ldc1 : gp.ldc0;
  const int M = g ? gp.M1 : gp.M0;
  const int K = g ? gp.K1 : gp.K0;
  const int act = g ? gp.act1 : gp.act0;
  const int isbf = g ? gp.bf1 : gp.bf0;
  const int nbn = g ? gp.nbn1 : gp.nbn0;
  const int brow = (w2 / nbn) * 128, bcol = (w2 % nbn) * 128;
  const int wr = w >> 1, wc = w & 1;

  f32x4 acc[4][4];
#pragma unroll
  for (int m = 0; m < 4; m++)
#pragma unroll
    for (int n = 0; n < 4; n++) acc[m][n] = (f32x4){0.f, 0.f, 0.f, 0.f};

  short* Asb = smem;
  short* Bsb = smem + 8192;
  const int nk = K >> 6;
  for (int t = 0; t < nk; t++) {
    const int k0 = t << 6;
#pragma unroll
    for (int i = 0; i < 4; i++) {
      int chunk = i * 4 + w;                   // wave-uniform
      int c_lin = chunk * 64 + lane;
      int row = c_lin >> 3;
      int kc = ((c_lin & 7) ^ (row & 7)) * 8;  // inverse-swizzled source k
      int growA = brow + row; growA = growA < M ? growA : M - 1;
      gload16(A + (size_t)growA * lda + k0 + kc, Asb + chunk * 512);
      gload16(Bt + (size_t)(bcol + row) * ldb + k0 + kc, Bsb + chunk * 512);
    }
    __syncthreads();   // drains vmcnt: staged tile visible
#pragma unroll
    for (int kk = 0; kk < 2; kk++) {
      const int ke = kk * 32 + (lane >> 4) * 8;
      bf16x8 af[4], bq[4];
#pragma unroll
      for (int m = 0; m < 4; m++) {
        int row = wr * 64 + m * 16 + (lane & 15);
        af[m] = *(const bf16x8*)(Asb + row * 64 + (ke ^ ((row & 7) << 3)));
      }
#pragma unroll
      for (int n = 0; n < 4; n++) {
        int col = wc * 64 + n * 16 + (lane & 15);
        bq[n] = *(const bf16x8*)(Bsb + col * 64 + (ke ^ ((col & 7) << 3)));
      }
#pragma unroll
      for (int m = 0; m < 4; m++)
#pragma unroll
        for (int n = 0; n < 4; n++)
          acc[m][n] = __builtin_amdgcn_mfma_f32_16x16x32_bf16(af[m], bq[n], acc[m][n], 0, 0, 0);
    }
    __syncthreads();   // all waves done reading before next stage overwrites
  }

  if (isbf) {
    // ---- two-half LDS-bounce epilogue (64x132 tile fits in 32KB union) ----
#pragma unroll
    for (int half = 0; half < 2; half++) {
      __syncthreads();
      if (wr == half) {
#pragma unroll
        for (int m = 0; m < 4; m++) {
          int rl0 = m * 16 + (lane >> 4) * 4;   // local row within half
#pragma unroll
          for (int n = 0; n < 4; n++) {
            int col = wc * 64 + n * 16 + (lane & 15);
            float bv = bias ? bias[bcol + col] : 0.f;
#pragma unroll
            for (int r = 0; r < 4; r++) {
              float v = acc[m][n][r] + bv;
              if (act) v = fmaxf(v, 0.f);
              smem[(rl0 + r) * TSTRIDE + col] = (short)f2bu(v);
            }
          }
        }
      }
      __syncthreads();
#pragma unroll
      for (int it = 0; it < 4; it++) {
        int chunk = it * 256 + tid;        // 0..1023 : 64 rows x 16 chunks of 16B
        int row = chunk >> 4, c16 = chunk & 15;
        int gr = brow + half * 64 + row;
        if (gr < M) {
          u32x4 v = *(const u32x4*)(smem + row * TSTRIDE + c16 * 8);
          __builtin_nontemporal_store(v,
              (u32x4*)((unsigned short*)Cv + (size_t)gr * ldc + bcol + c16 * 8));
        }
      }
    }
  } else {
    // fp32 C: direct NT (16 lanes x 4B = full 64B line)
#pragma unroll
    for (int m = 0; m < 4; m++) {
      int gr0 = brow + wr * 64 + m * 16 + (lane >> 4) * 4;
#pragma unroll
      for (int n = 0; n < 4; n++) {
        int gc = bcol + wc * 64 + n * 16 + (lane & 15);
        float bv = bias ? bias[gc] : 0.f;
#pragma unroll
        for (int r = 0; r < 4; r++) {
          int gr = gr0 + r;
          if (gr < M) {
            float v = acc[m][n][r] + bv;
            if (act) v = fmaxf(v, 0.f);
            __builtin_nontemporal_store(v, (float*)Cv + (size_t)gr * ldc + gc);
          }
        }
      }
    }
  }
}

// ---------------------------------------------------------------------------
// Weight preparation
// ---------------------------------------------------------------------------
struct FuseArgs {
  const float* W[12];
  const float* rel[12];
  const float* bin[12];
  float* out[12];
  float* bout[12];
};
struct TrArgs {
  const float* src[20];
  bf16* dst[20];
};
struct CopyB { const float* src[4]; float* dst[4]; };

__global__ __launch_bounds__(256)
void gemm_fuse(FuseArgs fa)
{
  int c = blockIdx.z >> 2, h = blockIdx.z & 3;
  const float* A = fa.W[c] + h * 128;
  const float* B = fa.rel[c] + (size_t)h * 128 * 128;
  float* C = fa.out[c] + h * 128;
  __shared__ float Ast[64][17];
  __shared__ float Bst[16][64];
  const int tid = threadIdx.x;
  const int tx = tid & 15, ty = tid >> 4;
  const int bm = blockIdx.x * 64, bn = blockIdx.y * 64;
  float acc[4][4] = {};
  for (int k0 = 0; k0 < 128; k0 += 16) {
#pragma unroll
    for (int i = 0; i < 4; i++) {
      int lin = tid + i * 256;
      int m = lin >> 4, kk = lin & 15;
      Ast[m][kk] = A[(size_t)(bm + m) * 512 + k0 + kk];
      int kb = lin >> 6, nb = lin & 63;
      Bst[kb][nb] = B[(size_t)(k0 + kb) * 128 + bn + nb];
    }
    __syncthreads();
#pragma unroll
    for (int kk = 0; kk < 16; kk++) {
      float a[4], b[4];
#pragma unroll
      for (int i = 0; i < 4; i++) a[i] = Ast[ty * 4 + i][kk];
#pragma unroll
      for (int j = 0; j < 4; j++) b[j] = Bst[kk][tx * 4 + j];
#pragma unroll
      for (int i = 0; i < 4; i++)
#pragma unroll
        for (int j = 0; j < 4; j++)
          acc[i][j] = fmaf(a[i], b[j], acc[i][j]);
    }
    __syncthreads();
  }
#pragma unroll
  for (int i = 0; i < 4; i++)
#pragma unroll
    for (int j = 0; j < 4; j++)
      C[(size_t)(bm + ty * 4 + i) * 512 + bn + tx * 4 + j] = acc[i][j];
}

__global__ __launch_bounds__(256)
void transpose20(TrArgs ta)
{
  int c = blockIdx.z;
  const float* in = ta.src[c];
  bf16* o = ta.dst[c];
  __shared__ float t[32][33];
  int bn = blockIdx.x * 32, bk = blockIdx.y * 32;
  int x = threadIdx.x, y = threadIdx.y;
#pragma unroll
  for (int i = 0; i < 32; i += 8)
    t[y + i][x] = in[(size_t)(bk + y + i) * 512 + bn + x];
  __syncthreads();
#pragma unroll
  for (int i = 0; i < 32; i += 8)
    o[(size_t)(bn + y + i) * 512 + bk + x] = __float2bfloat16(t[x][y + i]);
}

__global__ __launch_bounds__(512)
void bias_fuse_all(FuseArgs fa)
{
  int c = blockIdx.x;
  int j = threadIdx.x;
  int h = j >> 7, e = j & 127;
  const float* bh = fa.bin[c] + h * DH;
  const float* rh = fa.rel[c] + (size_t)h * DH * DH;
  float s = 0.f;
  for (int d = 0; d < DH; d++) s = fmaf(bh[d], rh[d * DH + e], s);
  fa.bout[c][j] = s;
}

__global__ __launch_bounds__(512)
void copy_bias(CopyB cb)
{
  cb.dst[blockIdx.x][threadIdx.x] = cb.src[blockIdx.x][threadIdx.x];
}

__global__ __launch_bounds__(256)
void transpose_to_bf16(const float* __restrict__ in, bf16* __restrict__ out,
                       int K_, int N_)
{
  __shared__ float t[32][33];
  int bn = blockIdx.x * 32, bk = blockIdx.y * 32;
  int x = threadIdx.x, y = threadIdx.y;
#pragma unroll
  for (int i = 0; i < 32; i += 8) {
    int k = bk + y + i, n = bn + x;
    if (k < K_ && n < N_) t[y + i][x] = in[(size_t)k * N_ + n];
  }
  __syncthreads();
#pragma unroll
  for (int i = 0; i < 32; i += 8) {
    int n = bn + y + i, k = bk + x;
    if (n < N_ && k < K_) out[(size_t)n * K_ + k] = __float2bfloat16(t[x][y + i]);
  }
}

__global__ __launch_bounds__(256)
void f32_to_bf16_2(const float* __restrict__ s0, bf16* __restrict__ d0, long long n0,
                   const float* __restrict__ s1, bf16* __restrict__ d1, long long n1)
{
  long long i = ((long long)blockIdx.x * 256 + threadIdx.x) * 4;
  const float* s; bf16* d;
  if (i < n0) { s = s0; d = d0; }
  else { i -= n0; if (i >= n1) return; s = s1; d = d1; }
  float4 v = *(const float4*)(s + i);
  ushort4 o;
  o.x = f2bu(v.x); o.y = f2bu(v.y); o.z = f2bu(v.z); o.w = f2bu(v.w);
  *(ushort4*)(d + i) = o;
}

// ---------------------------------------------------------------------------
// CSR build (merged launches)
// ---------------------------------------------------------------------------
__global__ __launch_bounds__(256)
void build_hist3(const int* __restrict__ eiC, const int* __restrict__ eiW,
                 const int* __restrict__ eiB,
                 int* __restrict__ degP, int* __restrict__ degA)
{
  int i = blockIdx.x * 256 + threadIdx.x;
  if (i < EC) atomicAdd(&degP[eiC[EC + i]], 1);
  else if (i < EC + EW) atomicAdd(&degP[eiW[EW + (i - EC)]], 1);
  else if (i < EC + EW + EB) atomicAdd(&degA[eiB[EB + (i - EC - EW)]], 1);
}

__device__ __forceinline__ void scan_blk_body(const int* __restrict__ deg, int n,
                                              int* __restrict__ rowptr,
                                              int* __restrict__ bsum, int blk)
{
  __shared__ int sh[256];
  int t = threadIdx.x;
  int base = blk * 1024 + t * 4;
  int v0 = 0, v1 = 0, v2 = 0, v3 = 0;
  if (base + 3 < n) {
    int4 v = *(const int4*)(deg + base);
    v0 = v.x; v1 = v.y; v2 = v.z; v3 = v.w;
  } else {
    if (base < n)     v0 = deg[base];
    if (base + 1 < n) v1 = deg[base + 1];
    if (base + 2 < n) v2 = deg[base + 2];
    if (base + 3 < n) v3 = deg[base + 3];
  }
  int s = v0 + v1 + v2 + v3;
  sh[t] = s;
  __syncthreads();
#pragma unroll
  for (int off = 1; off < 256; off <<= 1) {
    int tv = (t >= off) ? sh[t - off] : 0;
    __syncthreads();
    sh[t] += tv;
    __syncthreads();
  }
  int excl = sh[t] - s;
  if (t == 255) bsum[blk] = sh[255];
  if (base < n)     rowptr[base] = excl;
  if (base + 1 < n) rowptr[base + 1] = excl + v0;
  if (base + 2 < n) rowptr[base + 2] = excl + v0 + v1;
  if (base + 3 < n) rowptr[base + 3] = excl + v0 + v1 + v2;
}

#define NBP ((NP + 1023) / 1024)
#define NBA ((NA + 1023) / 1024)

__global__ __launch_bounds__(256)
void scan_blk2(const int* __restrict__ degP, int* __restrict__ rowptrP, int* __restrict__ bsumP,
               const int* __restrict__ degA, int* __restrict__ rowptrA, int* __restrict__ bsumA)
{
  if (blockIdx.x < NBP) scan_blk_body(degP, NP, rowptrP, bsumP, blockIdx.x);
  else                  scan_blk_body(degA, NA, rowptrA, bsumA, blockIdx.x - NBP);
}

__global__ __launch_bounds__(64)
void scan_bsum2(int* __restrict__ bsumP, int* __restrict__ endP,
                int* __restrict__ bsumA, int* __restrict__ endA)
{
  int* bsum = blockIdx.x ? bsumA : bsumP;
  int nb = blockIdx.x ? NBA : NBP;
  int* rpe = blockIdx.x ? endA : endP;
  int t = threadIdx.x;
  int v = (t < nb) ? bsum[t] : 0;
  int inc = v;
#pragma unroll
  for (int off = 1; off < 64; off <<= 1) {
    int o = __shfl_up(inc, off);
    if (t >= off) inc += o;
  }
  if (t < nb) bsum[t] = inc - v;
  if (t == nb - 1) *rpe = inc;
}

__global__ __launch_bounds__(256)
void scan_add2(int* __restrict__ rowptrP, const int* __restrict__ bsumP,
               int* __restrict__ rowptrA, const int* __restrict__ bsumA)
{
  int* rowptr; const int* bsum; int n, blk;
  if (blockIdx.x < NBP) { rowptr = rowptrP; bsum = bsumP; n = NP; blk = blockIdx.x; }
  else                  { rowptr = rowptrA; bsum = bsumA; n = NA; blk = blockIdx.x - NBP; }
  int add = bsum[blk];
  if (add == 0) return;
  int i = blk * 1024 + threadIdx.x * 4;
  if (i < n)     rowptr[i] += add;
  if (i + 1 < n) rowptr[i + 1] += add;
  if (i + 2 < n) rowptr[i + 2] += add;
  if (i + 3 < n) rowptr[i + 3] += add;
}

__global__ __launch_bounds__(256)
void build_scatter3(const int* __restrict__ eiC, const int* __restrict__ eiW,
                    const int* __restrict__ eiB,
                    const int* __restrict__ rowptrP, int* __restrict__ curP,
                    int* __restrict__ srcsP,
                    const int* __restrict__ rowptrA, int* __restrict__ curA,
                    int* __restrict__ srcsA)
{
  int i = blockIdx.x * 256 + threadIdx.x;
  if (i < EC) {
    int src = eiC[i], dst = eiC[EC + i];
    int pos = rowptrP[dst] + atomicAdd(&curP[dst], 1);
    srcsP[pos] = src;
  } else if (i < EC + EW) {
    int e = i - EC;
    int src = eiW[e], dst = eiW[EW + e];
    int pos = rowptrP[dst] + atomicAdd(&curP[dst], 1);
    srcsP[pos] = src | 0x40000000;
  } else if (i < EC + EW + EB) {
    int e = i - EC - EW;
    int src = eiB[e], dst = eiB[EB + e];
    int pos = rowptrA[dst] + atomicAdd(&curA[dst], 1);
    srcsA[pos] = src;
  }
}

// ---------------------------------------------------------------------------
// Merged fused one-pass attention (paper + author). Online softmax w/
// defer-max THR=8 + exact gelu -> bf16. One 64-lane wave per node.
// Edge loop 2-stage software-pipelined (next edge's K/V issued pre-compute).
// ---------------------------------------------------------------------------
__global__ __launch_bounds__(256)
void csr_attn_agg2(const int* __restrict__ rowptrP, const int* __restrict__ srcsP,
                   const int* __restrict__ rowptrA, const int* __restrict__ srcsA,
                   const bf16* __restrict__ qkvP, const bf16* __restrict__ qkvA,
                   const float* __restrict__ prl, float scale,
                   bf16* __restrict__ agP, bf16* __restrict__ agA)
{
  int node = blockIdx.x * 4 + (threadIdx.x >> 6);
  int lane = threadIdx.x & 63;
  int h = lane >> 4;
  const int* rp; const int* srcs;
  const bf16* q; const bf16 *t0, *t1;
  int ld0, off0, ld1, off1;
  float p0, p1;
  bf16* outp;
  if (node < NP) {
    rp = rowptrP; srcs = srcsP;
    q = qkvP + (size_t)node * NQP;
    t0 = qkvP; ld0 = NQP; off0 = 512;
    t1 = qkvA; ld1 = NQA; off1 = 512;
    p0 = prl[h] * scale; p1 = prl[4 + h] * scale;
    outp = agP + (size_t)node * HID;
  } else {
    int r = node - NP;
    if (r >= NA) return;
    rp = rowptrA; srcs = srcsA; node = r;
    q = qkvA + (size_t)r * NQA;
    t0 = qkvP; ld0 = NQP; off0 = 1536;
    t1 = qkvP; ld1 = NQP; off1 = 1536;
    p0 = prl[8 + h] * scale; p1 = p0;
    outp = agA + (size_t)r * HID;
  }
  float qv[8];
  load8b(q, lane, qv);
  int beg = rp[node], end = rp[node + 1];
  float m = -INFINITY, s = 0.f;
  float acc[8] = {};
  float kv[8], vv[8];
  int se = 0;
  if (beg < end) {
    se = srcs[beg];
    int src = se & 0x3FFFFFFF;
    const bf16* row = (se & 0x40000000) ? (t1 + (size_t)src * ld1 + off1)
                                        : (t0 + (size_t)src * ld0 + off0);
    load8b(row, lane, kv);
    load8b(row + 512, lane, vv);
  }
  for (int p = beg; p < end; ++p) {
    bool f1 = (se & 0x40000000) != 0;
    float ckv[8], cvv[8];
#pragma unroll
    for (int i = 0; i < 8; i++) { ckv[i] = kv[i]; cvv[i] = vv[i]; }
    if (p + 1 < end) {
      se = srcs[p + 1];
      int src = se & 0x3FFFFFFF;
      const bf16* row = (se & 0x40000000) ? (t1 + (size_t)src * ld1 + off1)
                                          : (t0 + (size_t)src * ld0 + off0);
      load8b(row, lane, kv);        // issue next-edge loads before compute
      load8b(row + 512, lane, vv);
    }
    float a = 0.f;
#pragma unroll
    for (int i = 0; i < 8; i++) a = fmaf(qv[i], ckv[i], a);
    a += __shfl_xor(a, 1);
    a += __shfl_xor(a, 2);
    a += __shfl_xor(a, 4);
    a += __shfl_xor(a, 8);
    a *= f1 ? p1 : p0;
    if (a > m + 8.f) {              // defer-max (T13)
      float sc = __expf(m - a);
      s *= sc;
#pragma unroll
      for (int i = 0; i < 8; i++) acc[i] *= sc;
      m = a;
    }
    float wgt = __expf(a - m);
    s += wgt;
#pragma unroll
    for (int i = 0; i < 8; i++) acc[i] = fmaf(wgt, cvv[i], acc[i]);
  }
  float inv = 1.f / (s + 1e-16f);
  unsigned short gg[8];
#pragma unroll
  for (int i = 0; i < 8; i++) {
    float v = acc[i] * inv;
    gg[i] = f2bu(0.5f * v * (1.f + erff(v * 0.70710678118654752f)));
  }
  uint4 o;
  o.x = gg[0] | ((unsigned)gg[1] << 16);
  o.y = gg[2] | ((unsigned)gg[3] << 16);
  o.z = gg[4] | ((unsigned)gg[5] << 16);
  o.w = gg[6] | ((unsigned)gg[7] << 16);
  *(uint4*)(outp + lane * 8) = o;
}

// merged skip+residual+LN+relu (paper + author); oplin bf16, h bf16 in/out
__global__ __launch_bounds__(256)
void skip_ln_relu2(const bf16* __restrict__ oplP, const bf16* __restrict__ oplA,
                   bf16* __restrict__ hP, bf16* __restrict__ hA,
                   const float* __restrict__ skip2,
                   const float* __restrict__ g, const float* __restrict__ b)
{
  int row = blockIdx.x;
  const bf16* orow; bf16* hrow; float sk;
  if (row < NP) {
    orow = oplP + (size_t)row * HID; hrow = hP + (size_t)row * HID; sk = skip2[0];
  } else {
    int r = row - NP;
    orow = oplA + (size_t)r * HID; hrow = hA + (size_t)r * HID; sk = skip2[1];
  }
  float sp = 1.f / (1.f + expf(-sk));
  int t = threadIdx.x;
  ushort2 ov = ((const ushort2*)orow)[t];
  ushort2 hv = ((ushort2*)hrow)[t];
  float t0 = sp * bu2f(ov.x) + (2.f - sp) * bu2f(hv.x);
  float t1 = sp * bu2f(ov.y) + (2.f - sp) * bu2f(hv.y);
  float s = t0 + t1, ss = t0 * t0 + t1 * t1;
#pragma unroll
  for (int off = 32; off; off >>= 1) {
    s += __shfl_down(s, off);
    ss += __shfl_down(ss, off);
  }
  __shared__ float sh[8];
  int wid = t >> 6, lane = t & 63;
  if (lane == 0) { sh[wid] = s; sh[4 + wid] = ss; }
  __syncthreads();
  if (t == 0) {
    float S = 0, SS = 0;
    for (int wv = 0; wv < 4; wv++) { S += sh[wv]; SS += sh[4 + wv]; }
    sh[0] = S; sh[4] = SS;
  }
  __syncthreads();
  float mu = sh[0] * (1.f / 512.f);
  float var = sh[4] * (1.f / 512.f) - mu * mu;
  float inv = rsqrtf(var + 1e-5f);
  float y0 = (t0 - mu) * inv * g[2 * t] + b[2 * t];
  float y1 = (t1 - mu) * inv * g[2 * t + 1] + b[2 * t + 1];
  ushort2 o;
  o.x = f2bu(fmaxf(y0, 0.f));
  o.y = f2bu(fmaxf(y1, 0.f));
  ((ushort2*)hrow)[t] = o;
}

// ---------------------------------------------------------------------------
static inline void mgemm2(GemmPair gp, int N0, int N1, hipStream_t s)
{
  gp.nbn0 = N0 / 128;
  gp.nbn1 = N1 / 128;
  int nw0 = ((gp.M0 + 127) / 128) * gp.nbn0;
  int nw1 = ((gp.M1 + 127) / 128) * gp.nbn1;
  gp.nw0 = nw0;
  mfma_gemm2<<<dim3(nw0 + nw1), 256, 0, s>>>(gp);
}

extern "C" void kernel_launch(void* const* d_in, const int* in_sizes, int n_in,
                              void* d_out, int out_size, void* d_ws, size_t ws_size,
                              hipStream_t stream)
{
  const float* x_paper  = (const float*)d_in[0];
  const float* x_author = (const float*)d_in[1];
  const float* Wp_paper = (const float*)d_in[2];
  const float* bp_paper = (const float*)d_in[3];
  const float* Wp_author= (const float*)d_in[4];
  const float* bp_author= (const float*)d_in[5];
  const float* Wk = (const float*)d_in[6];
  const float* bk = (const float*)d_in[7];
  const float* Wq = (const float*)d_in[8];
  const float* bq = (const float*)d_in[9];
  const float* Wv = (const float*)d_in[10];
  const float* bv = (const float*)d_in[11];
  const float* Wa = (const float*)d_in[12];
  const float* ba = (const float*)d_in[13];
  const float* skip = (const float*)d_in[14];
  const float* a_rel = (const float*)d_in[15];
  const float* m_rel = (const float*)d_in[16];
  const float* p_rel = (const float*)d_in[17];
  const float* ln_g = (const float*)d_in[18];
  const float* ln_b = (const float*)d_in[19];
  const float* W256 = (const float*)d_in[20];
  const float* b256 = (const float*)d_in[21];
  const float* W128 = (const float*)d_in[22];
  const float* b128 = (const float*)d_in[23];
  const int* ei_c = (const int*)d_in[24];
  const int* ei_w = (const int*)d_in[25];
  const int* ei_b = (const int*)d_in[26];
  float* out = (float*)d_out;

  const size_t NPe = (size_t)NP * HID, NAe = (size_t)NA * HID;
  const size_t HH = (size_t)HID * HID;
  char* w = (char*)d_ws;
  size_t off = 0;
  auto alloc = [&](size_t bytes) -> void* {
    void* p = (void*)(w + off);
    off += (bytes + 255) & ~(size_t)255;
    return p;
  };
  bf16* hb_p  = (bf16*)alloc(NPe * 2);
  bf16* hb_a  = (bf16*)alloc(NAe * 2);
  bf16* qkv_p = (bf16*)alloc((size_t)NP * NQP * 2);
  bf16* qkv_a = (bf16*)alloc((size_t)NA * NQA * 2);
  bf16* ag_p  = (bf16*)alloc(NPe * 2);
  bf16* ag_a  = (bf16*)alloc(NAe * 2);
  float* Wf32 = (float*)alloc(12 * HH * 4);
  bf16* WBtP  = (bf16*)alloc((size_t)2 * NQP * HID * 2);
  bf16* WBtA  = (bf16*)alloc((size_t)2 * NQA * HID * 2);
  float* pbP  = (float*)alloc((size_t)2 * NQP * 4);
  float* pbA  = (float*)alloc((size_t)2 * NQA * 4);
  bf16* WaT   = (bf16*)alloc(4 * HH * 2);
  bf16* W256T = (bf16*)alloc((size_t)HID * 256 * 2);
  bf16* W128T = (bf16*)alloc((size_t)256 * 128 * 2);
  bf16* WpTp  = (bf16*)alloc((size_t)INDIM * HID * 2);
  bf16* WpTa  = (bf16*)alloc((size_t)INDIM * HID * 2);
  int* rowptrP = (int*)alloc((size_t)(NP + 1) * 4);
  int* rowptrA = (int*)alloc((size_t)(NA + 1) * 4);
  int* degP    = (int*)alloc((size_t)(2 * NP + 2 * NA) * 4);  // degP|degA|curP|curA
  int* degA    = degP + NP;
  int* curP    = degA + NA;
  int* curA    = curP + NP;
  int* srcsP   = (int*)alloc((size_t)(EC + EW) * 4);
  int* srcsA   = (int*)alloc((size_t)EB * 4);
  int* bsumP   = (int*)alloc(64 * 4);
  int* bsumA   = (int*)alloc(64 * 4);
  if (off > ws_size) return;

  const float scale = 0.08838834764831845f;  // 1/sqrt(128)

  // --- CSR build (merged launches) ---
  (void)hipMemsetAsync(degP, 0, (size_t)(2 * NP + 2 * NA) * 4, stream);
  build_hist3<<<dim3((EC + EW + EB + 255) / 256), 256, 0, stream>>>(ei_c, ei_w, ei_b, degP, degA);
  scan_blk2<<<dim3(NBP + NBA), 256, 0, stream>>>(degP, rowptrP, bsumP, degA, rowptrA, bsumA);
  scan_bsum2<<<dim3(2), 64, 0, stream>>>(bsumP, rowptrP + NP, bsumA, rowptrA + NA);
  scan_add2<<<dim3(NBP + NBA), 256, 0, stream>>>(rowptrP, bsumP, rowptrA, bsumA);
  build_scatter3<<<dim3((EC + EW + EB + 255) / 256), 256, 0, stream>>>(
      ei_c, ei_w, ei_b, rowptrP, curP, srcsP, rowptrA, curA, srcsA);

  // --- fused relation weights + layer packs ---
  FuseArgs fa;
  TrArgs ta;
  CopyB cb;
  for (int l = 0; l < NLAY; l++) {
    bf16* packP = WBtP + (size_t)l * NQP * HID;
    bf16* packA = WBtA + (size_t)l * NQA * HID;
    float* pbPl = pbP + (size_t)l * NQP;
    float* pbAl = pbA + (size_t)l * NQA;
    for (int r = 0; r < 3; r++)
      for (int s = 0; s < 2; s++) {
        int c = (l * 3 + r) * 2 + s;
        int t = (r == 1) ? 1 : 0;
        fa.W[c]   = (s == 0 ? Wk : Wv) + (size_t)(l * 2 + t) * HH;
        fa.rel[c] = (s == 0 ? a_rel : m_rel) + (size_t)(l * 3 + r) * NHEAD * DH * DH;
        fa.bin[c] = (s == 0 ? bk : bv) + (size_t)(l * 2 + t) * HID;
        fa.out[c] = Wf32 + (size_t)c * HH;
        ta.src[c] = fa.out[c];
        if (r == 0) {
          ta.dst[c]  = packP + (size_t)(512 + s * 512) * HID;
          fa.bout[c] = pbPl + 512 + s * 512;
        } else if (r == 1) {
          ta.dst[c]  = packA + (size_t)(512 + s * 512) * HID;
          fa.bout[c] = pbAl + 512 + s * 512;
        } else {
          ta.dst[c]  = packP + (size_t)(1536 + s * 512) * HID;
          fa.bout[c] = pbPl + 1536 + s * 512;
        }
      }
    ta.src[12 + l * 2 + 0] = Wq + (size_t)(l * 2 + 0) * HH;
    ta.dst[12 + l * 2 + 0] = packP;
    ta.src[12 + l * 2 + 1] = Wq + (size_t)(l * 2 + 1) * HH;
    ta.dst[12 + l * 2 + 1] = packA;
    ta.src[16 + l * 2 + 0] = Wa + (size_t)(l * 2 + 0) * HH;
    ta.dst[16 + l * 2 + 0] = WaT + (size_t)(l * 2 + 0) * HH;
    ta.src[16 + l * 2 + 1] = Wa + (size_t)(l * 2 + 1) * HH;
    ta.dst[16 + l * 2 + 1] = WaT + (size_t)(l * 2 + 1) * HH;
    cb.src[l * 2 + 0] = bq + (size_t)(l * 2 + 0) * HID;
    cb.dst[l * 2 + 0] = pbPl;
    cb.src[l * 2 + 1] = bq + (size_t)(l * 2 + 1) * HID;
    cb.dst[l * 2 + 1] = pbAl;
  }
  gemm_fuse<<<dim3(8, 2, 48), 256, 0, stream>>>(fa);
  transpose20<<<dim3(16, 16, 20), dim3(32, 8), 0, stream>>>(ta);
  bias_fuse_all<<<dim3(12), 512, 0, stream>>>(fa);
  copy_bias<<<dim3(4), 512, 0, stream>>>(cb);
  {
    dim3 b(32, 8);
    transpose_to_bf16<<<dim3(8, 16), b, 0, stream>>>(W256, W256T, HID, 256);
    transpose_to_bf16<<<dim3(4, 8), b, 0, stream>>>(W128, W128T, 256, 128);
    transpose_to_bf16<<<dim3(16, 24), b, 0, stream>>>(Wp_paper, WpTp, INDIM, HID);
    transpose_to_bf16<<<dim3(16, 24), b, 0, stream>>>(Wp_author, WpTa, INDIM, HID);
  }

  // --- input conversion + projection ---
  bf16* xb_p = qkv_p;
  bf16* xb_a = qkv_a;
  long long nxp = (long long)NP * INDIM, nxa = (long long)NA * INDIM;
  f32_to_bf16_2<<<dim3((int)(((nxp + nxa) / 4 + 255) / 256)), 256, 0, stream>>>(
      x_paper, xb_p, nxp, x_author, xb_a, nxa);
  {
    GemmPair gp{};
    gp.A0 = xb_p; gp.lda0 = INDIM; gp.B0 = WpTp; gp.ldb0 = INDIM;
    gp.b0 = bp_paper; gp.C0 = hb_p; gp.ldc0 = HID;
    gp.M0 = NP; gp.K0 = INDIM; gp.act0 = 0; gp.bf0 = 1;
    gp.A1 = xb_a; gp.lda1 = INDIM; gp.B1 = WpTa; gp.ldb1 = INDIM;
    gp.b1 = bp_author; gp.C1 = hb_a; gp.ldc1 = HID;
    gp.M1 = NA; gp.K1 = INDIM; gp.act1 = 0; gp.bf1 = 1;
    mgemm2(gp, HID, HID, stream);
  }

  for (int l = 0; l < NLAY; l++) {
    const float* prl = p_rel + (size_t)l * 3 * NHEAD;
    const bf16* packP = WBtP + (size_t)l * NQP * HID;
    const bf16* packA = WBtA + (size_t)l * NQA * HID;
    const float* pbPl = pbP + (size_t)l * NQP;
    const float* pbAl = pbA + (size_t)l * NQA;

    // fused projections pair: q|kv0|kv2 (paper) + q|kv1 (author)
    {
      GemmPair gp{};
      gp.A0 = hb_p; gp.lda0 = HID; gp.B0 = packP; gp.ldb0 = HID;
      gp.b0 = pbPl; gp.C0 = qkv_p; gp.ldc0 = NQP;
      gp.M0 = NP; gp.K0 = HID; gp.act0 = 0; gp.bf0 = 1;
      gp.A1 = hb_a; gp.lda1 = HID; gp.B1 = packA; gp.ldb1 = HID;
      gp.b1 = pbAl; gp.C1 = qkv_a; gp.ldc1 = NQA;
      gp.M1 = NA; gp.K1 = HID; gp.act1 = 0; gp.bf1 = 1;
      mgemm2(gp, NQP, NQA, stream);
    }
    // merged one-pass attention + gelu
    csr_attn_agg2<<<dim3((NP + NA + 3) / 4), 256, 0, stream>>>(
        rowptrP, srcsP, rowptrA, srcsA, qkv_p, qkv_a, prl, scale, ag_p, ag_a);
    // output linear pair (bf16 out into dead qkv slabs)
    bf16* opl_p = qkv_p;
    bf16* opl_a = qkv_a;
    {
      GemmPair gp{};
      gp.A0 = ag_p; gp.lda0 = HID; gp.B0 = WaT + (size_t)(l * 2 + 0) * HH; gp.ldb0 = HID;
      gp.b0 = ba + (size_t)(l * 2 + 0) * HID; gp.C0 = opl_p; gp.ldc0 = HID;
      gp.M0 = NP; gp.K0 = HID; gp.act0 = 0; gp.bf0 = 1;
      gp.A1 = ag_a; gp.lda1 = HID; gp.B1 = WaT + (size_t)(l * 2 + 1) * HH; gp.ldb1 = HID;
      gp.b1 = ba + (size_t)(l * 2 + 1) * HID; gp.C1 = opl_a; gp.ldc1 = HID;
      gp.M1 = NA; gp.K1 = HID; gp.act1 = 0; gp.bf1 = 1;
      mgemm2(gp, HID, HID, stream);
    }
    // merged skip + residual + LN + relu
    skip_ln_relu2<<<dim3(NP + NA), 256, 0, stream>>>(
        opl_p, opl_a, hb_p, hb_a, skip + l * 2,
        ln_g + (size_t)l * HID, ln_b + (size_t)l * HID);
  }

  // final MLP
  bf16* h256_p = ag_p;
  bf16* h256_a = ag_a;
  {
    GemmPair gp{};
    gp.A0 = hb_p; gp.lda0 = HID; gp.B0 = W256T; gp.ldb0 = HID;
    gp.b0 = b256; gp.C0 = h256_p; gp.ldc0 = 256;
    gp.M0 = NP; gp.K0 = HID; gp.act0 = 1; gp.bf0 = 1;
    gp.A1 = hb_a; gp.lda1 = HID; gp.B1 = W256T; gp.ldb1 = HID;
    gp.b1 = b256; gp.C1 = h256_a; gp.ldc1 = 256;
    gp.M1 = NA; gp.K1 = HID; gp.act1 = 1; gp.bf1 = 1;
    mgemm2(gp, 256, 256, stream);
  }
  {
    GemmPair gp{};
    gp.A0 = h256_p; gp.lda0 = 256; gp.B0 = W128T; gp.ldb0 = 256;
    gp.b0 = b128; gp.C0 = out; gp.ldc0 = 128;
    gp.M0 = NP; gp.K0 = 256; gp.act0 = 0; gp.bf0 = 0;
    gp.A1 = h256_a; gp.lda1 = 256; gp.B1 = W128T; gp.ldb1 = 256;
    gp.b1 = b128; gp.C1 = out + (size_t)NP * 128; gp.ldc1 = 128;
    gp.M1 = NA; gp.K1 = 256; gp.act1 = 0; gp.bf1 = 0;
    mgemm2(gp, 128, 128, stream);
  }
}

// Round 16
// 846.444 us; speedup vs baseline: 1.0538x; 1.0538x over previous
//
#include <hip/hip_runtime.h>
#include <hip/hip_bf16.h>
#include <math.h>

#define NHEAD 4
#define DH 128
#define HID 512
#define NLAY 2
#define NP 30000
#define NA 10000
#define INDIM 768
#define EC 150000
#define EW 80000
#define EB 80000
#define NQP 2560   // q | kv0 | kv2
#define NQA 1536   // q | kv1

typedef __hip_bfloat16 bf16;
typedef __attribute__((ext_vector_type(8))) short bf16x8;
typedef __attribute__((ext_vector_type(4))) float f32x4;
typedef __attribute__((ext_vector_type(4))) unsigned int u32x4;

__device__ __forceinline__ unsigned short f2bu(float f){ bf16 t = __float2bfloat16(f); return *(unsigned short*)&t; }
__device__ __forceinline__ float bu2f(unsigned short u){ return __uint_as_float((unsigned)u << 16); }

__device__ __forceinline__ void load8b(const bf16* __restrict__ p, int i8, float* o){
  uint4 r = ((const uint4*)p)[i8];
  o[0]=__uint_as_float(r.x<<16); o[1]=__uint_as_float(r.x&0xffff0000u);
  o[2]=__uint_as_float(r.y<<16); o[3]=__uint_as_float(r.y&0xffff0000u);
  o[4]=__uint_as_float(r.z<<16); o[5]=__uint_as_float(r.z&0xffff0000u);
  o[6]=__uint_as_float(r.w<<16); o[7]=__uint_as_float(r.w&0xffff0000u);
}

// async global->LDS, 16B per lane, wave-uniform LDS base + lane*16
__device__ __forceinline__ void gload16(const void* g, void* l) {
  __builtin_amdgcn_global_load_lds((const __attribute__((address_space(1))) void*)g,
                                   (__attribute__((address_space(3))) void*)l, 16, 0, 0);
}

// ---------------------------------------------------------------------------
// Paired MFMA bf16 GEMM (round-12 proven form): two sub-GEMMs in ONE launch.
// 128x128 tile, BK=64, single-buffered 33.8KB LDS -> 4 blocks/CU; cross-block
// TLP hides the stage->barrier drain (m114). Inline per-iteration addressing
// (hoisting regressed r13; two-half epilogue regressed r15; dbuf regressed
// r11 -- this exact configuration is the schedule-local optimum).
// bf16 C: full-tile LDS-bounce epilogue -> 16B/lane NT stores. fp32 C: NT.
// ---------------------------------------------------------------------------
struct GemmPair {
  const bf16 *A0, *A1, *B0, *B1;
  const float *b0, *b1;
  void *C0, *C1;
  int lda0, lda1, ldb0, ldb1, ldc0, ldc1;
  int M0, M1, K0, K1;
  int act0, act1, bf0, bf1;      // bfX: 1 = bf16 C, 0 = fp32 C
  int nbn0, nbn1, nw0;
};

#define TSTRIDE 132   // padded bf16 epilogue stride

__global__ __launch_bounds__(256)
void mfma_gemm2(GemmPair gp)
{
  __shared__ __align__(16) short smem[128 * TSTRIDE];  // 33.8 KB
  const int tid = threadIdx.x;
  const int lane = tid & 63, w = tid >> 6;
  const int nwg = gridDim.x;
  const int bid = blockIdx.x;
  const int xcd = bid & 7, pos = bid >> 3;
  const int q8 = nwg >> 3, r8 = nwg & 7;
  const int work = (xcd < r8 ? xcd * (q8 + 1) : r8 * (q8 + 1) + (xcd - r8) * q8) + pos;
  const int g = work >= gp.nw0;
  const int w2 = g ? work - gp.nw0 : work;
  const bf16* A  = g ? gp.A1 : gp.A0;
  const bf16* Bt = g ? gp.B1 : gp.B0;
  const float* bias = g ? gp.b1 : gp.b0;
  void* Cv = g ? gp.C1 : gp.C0;
  const int lda = g ? gp.lda1 : gp.lda0;
  const int ldb = g ? gp.ldb1 : gp.ldb0;
  const int ldc = g ? gp.ldc1 : gp.ldc0;
  const int M = g ? gp.M1 : gp.M0;
  const int K = g ? gp.K1 : gp.K0;
  const int act = g ? gp.act1 : gp.act0;
  const int isbf = g ? gp.bf1 : gp.bf0;
  const int nbn = g ? gp.nbn1 : gp.nbn0;
  const int brow = (w2 / nbn) * 128, bcol = (w2 % nbn) * 128;
  const int wr = w >> 1, wc = w & 1;

  f32x4 acc[4][4];
#pragma unroll
  for (int m = 0; m < 4; m++)
#pragma unroll
    for (int n = 0; n < 4; n++) acc[m][n] = (f32x4){0.f, 0.f, 0.f, 0.f};

  short* Asb = smem;
  short* Bsb = smem + 8192;
  const int nk = K >> 6;
  for (int t = 0; t < nk; t++) {
    const int k0 = t << 6;
#pragma unroll
    for (int i = 0; i < 4; i++) {
      int chunk = i * 4 + w;                   // wave-uniform
      int c_lin = chunk * 64 + lane;
      int row = c_lin >> 3;
      int kc = ((c_lin & 7) ^ (row & 7)) * 8;  // inverse-swizzled source k
      int growA = brow + row; growA = growA < M ? growA : M - 1;
      gload16(A + (size_t)growA * lda + k0 + kc, Asb + chunk * 512);
      gload16(Bt + (size_t)(bcol + row) * ldb + k0 + kc, Bsb + chunk * 512);
    }
    __syncthreads();   // drains vmcnt: staged tile visible
#pragma unroll
    for (int kk = 0; kk < 2; kk++) {
      const int ke = kk * 32 + (lane >> 4) * 8;
      bf16x8 af[4], bq[4];
#pragma unroll
      for (int m = 0; m < 4; m++) {
        int row = wr * 64 + m * 16 + (lane & 15);
        af[m] = *(const bf16x8*)(Asb + row * 64 + (ke ^ ((row & 7) << 3)));
      }
#pragma unroll
      for (int n = 0; n < 4; n++) {
        int col = wc * 64 + n * 16 + (lane & 15);
        bq[n] = *(const bf16x8*)(Bsb + col * 64 + (ke ^ ((col & 7) << 3)));
      }
#pragma unroll
      for (int m = 0; m < 4; m++)
#pragma unroll
        for (int n = 0; n < 4; n++)
          acc[m][n] = __builtin_amdgcn_mfma_f32_16x16x32_bf16(af[m], bq[n], acc[m][n], 0, 0, 0);
    }
    __syncthreads();   // all waves done reading before next stage overwrites
  }

  if (isbf) {
    // ---- LDS-bounce epilogue ----
#pragma unroll
    for (int m = 0; m < 4; m++) {
      int row0 = wr * 64 + m * 16 + (lane >> 4) * 4;
#pragma unroll
      for (int n = 0; n < 4; n++) {
        int col = wc * 64 + n * 16 + (lane & 15);
        float bv = bias ? bias[bcol + col] : 0.f;
#pragma unroll
        for (int r = 0; r < 4; r++) {
          float v = acc[m][n][r] + bv;
          if (act) v = fmaxf(v, 0.f);
          smem[(row0 + r) * TSTRIDE + col] = (short)f2bu(v);
        }
      }
    }
    __syncthreads();
#pragma unroll
    for (int it = 0; it < 8; it++) {
      int chunk = it * 256 + tid;        // 0..2047 : 128 rows x 16 chunks of 16B
      int row = chunk >> 4, c16 = chunk & 15;
      int gr = brow + row;
      if (gr < M) {
        u32x4 v = *(const u32x4*)(smem + row * TSTRIDE + c16 * 8);
        __builtin_nontemporal_store(v,
            (u32x4*)((unsigned short*)Cv + (size_t)gr * ldc + bcol + c16 * 8));
      }
    }
  } else {
    // fp32 C: direct NT (16 lanes x 4B = full 64B line)
#pragma unroll
    for (int m = 0; m < 4; m++) {
      int gr0 = brow + wr * 64 + m * 16 + (lane >> 4) * 4;
#pragma unroll
      for (int n = 0; n < 4; n++) {
        int gc = bcol + wc * 64 + n * 16 + (lane & 15);
        float bv = bias ? bias[gc] : 0.f;
#pragma unroll
        for (int r = 0; r < 4; r++) {
          int gr = gr0 + r;
          if (gr < M) {
            float v = acc[m][n][r] + bv;
            if (act) v = fmaxf(v, 0.f);
            __builtin_nontemporal_store(v, (float*)Cv + (size_t)gr * ldc + gc);
          }
        }
      }
    }
  }
}

// ---------------------------------------------------------------------------
// Weight preparation
// ---------------------------------------------------------------------------
struct FuseArgs {
  const float* W[12];
  const float* rel[12];
  const float* bin[12];
  float* out[12];
  float* bout[12];
};
struct TrArgs {
  const float* src[20];
  bf16* dst[20];
};
struct CopyB { const float* src[4]; float* dst[4]; };

__global__ __launch_bounds__(256)
void gemm_fuse(FuseArgs fa)
{
  int c = blockIdx.z >> 2, h = blockIdx.z & 3;
  const float* A = fa.W[c] + h * 128;
  const float* B = fa.rel[c] + (size_t)h * 128 * 128;
  float* C = fa.out[c] + h * 128;
  __shared__ float Ast[64][17];
  __shared__ float Bst[16][64];
  const int tid = threadIdx.x;
  const int tx = tid & 15, ty = tid >> 4;
  const int bm = blockIdx.x * 64, bn = blockIdx.y * 64;
  float acc[4][4] = {};
  for (int k0 = 0; k0 < 128; k0 += 16) {
#pragma unroll
    for (int i = 0; i < 4; i++) {
      int lin = tid + i * 256;
      int m = lin >> 4, kk = lin & 15;
      Ast[m][kk] = A[(size_t)(bm + m) * 512 + k0 + kk];
      int kb = lin >> 6, nb = lin & 63;
      Bst[kb][nb] = B[(size_t)(k0 + kb) * 128 + bn + nb];
    }
    __syncthreads();
#pragma unroll
    for (int kk = 0; kk < 16; kk++) {
      float a[4], b[4];
#pragma unroll
      for (int i = 0; i < 4; i++) a[i] = Ast[ty * 4 + i][kk];
#pragma unroll
      for (int j = 0; j < 4; j++) b[j] = Bst[kk][tx * 4 + j];
#pragma unroll
      for (int i = 0; i < 4; i++)
#pragma unroll
        for (int j = 0; j < 4; j++)
          acc[i][j] = fmaf(a[i], b[j], acc[i][j]);
    }
    __syncthreads();
  }
#pragma unroll
  for (int i = 0; i < 4; i++)
#pragma unroll
    for (int j = 0; j < 4; j++)
      C[(size_t)(bm + ty * 4 + i) * 512 + bn + tx * 4 + j] = acc[i][j];
}

__global__ __launch_bounds__(256)
void transpose20(TrArgs ta)
{
  int c = blockIdx.z;
  const float* in = ta.src[c];
  bf16* o = ta.dst[c];
  __shared__ float t[32][33];
  int bn = blockIdx.x * 32, bk = blockIdx.y * 32;
  int x = threadIdx.x, y = threadIdx.y;
#pragma unroll
  for (int i = 0; i < 32; i += 8)
    t[y + i][x] = in[(size_t)(bk + y + i) * 512 + bn + x];
  __syncthreads();
#pragma unroll
  for (int i = 0; i < 32; i += 8)
    o[(size_t)(bn + y + i) * 512 + bk + x] = __float2bfloat16(t[x][y + i]);
}

__global__ __launch_bounds__(512)
void bias_fuse_all(FuseArgs fa)
{
  int c = blockIdx.x;
  int j = threadIdx.x;
  int h = j >> 7, e = j & 127;
  const float* bh = fa.bin[c] + h * DH;
  const float* rh = fa.rel[c] + (size_t)h * DH * DH;
  float s = 0.f;
  for (int d = 0; d < DH; d++) s = fmaf(bh[d], rh[d * DH + e], s);
  fa.bout[c][j] = s;
}

__global__ __launch_bounds__(512)
void copy_bias(CopyB cb)
{
  cb.dst[blockIdx.x][threadIdx.x] = cb.src[blockIdx.x][threadIdx.x];
}

__global__ __launch_bounds__(256)
void transpose_to_bf16(const float* __restrict__ in, bf16* __restrict__ out,
                       int K_, int N_)
{
  __shared__ float t[32][33];
  int bn = blockIdx.x * 32, bk = blockIdx.y * 32;
  int x = threadIdx.x, y = threadIdx.y;
#pragma unroll
  for (int i = 0; i < 32; i += 8) {
    int k = bk + y + i, n = bn + x;
    if (k < K_ && n < N_) t[y + i][x] = in[(size_t)k * N_ + n];
  }
  __syncthreads();
#pragma unroll
  for (int i = 0; i < 32; i += 8) {
    int n = bn + y + i, k = bk + x;
    if (n < N_ && k < K_) out[(size_t)n * K_ + k] = __float2bfloat16(t[x][y + i]);
  }
}

__global__ __launch_bounds__(256)
void f32_to_bf16_2(const float* __restrict__ s0, bf16* __restrict__ d0, long long n0,
                   const float* __restrict__ s1, bf16* __restrict__ d1, long long n1)
{
  long long i = ((long long)blockIdx.x * 256 + threadIdx.x) * 4;
  const float* s; bf16* d;
  if (i < n0) { s = s0; d = d0; }
  else { i -= n0; if (i >= n1) return; s = s1; d = d1; }
  float4 v = *(const float4*)(s + i);
  ushort4 o;
  o.x = f2bu(v.x); o.y = f2bu(v.y); o.z = f2bu(v.z); o.w = f2bu(v.w);
  *(ushort4*)(d + i) = o;
}

// ---------------------------------------------------------------------------
// CSR build (merged launches)
// ---------------------------------------------------------------------------
__global__ __launch_bounds__(256)
void build_hist3(const int* __restrict__ eiC, const int* __restrict__ eiW,
                 const int* __restrict__ eiB,
                 int* __restrict__ degP, int* __restrict__ degA)
{
  int i = blockIdx.x * 256 + threadIdx.x;
  if (i < EC) atomicAdd(&degP[eiC[EC + i]], 1);
  else if (i < EC + EW) atomicAdd(&degP[eiW[EW + (i - EC)]], 1);
  else if (i < EC + EW + EB) atomicAdd(&degA[eiB[EB + (i - EC - EW)]], 1);
}

__device__ __forceinline__ void scan_blk_body(const int* __restrict__ deg, int n,
                                              int* __restrict__ rowptr,
                                              int* __restrict__ bsum, int blk)
{
  __shared__ int sh[256];
  int t = threadIdx.x;
  int base = blk * 1024 + t * 4;
  int v0 = 0, v1 = 0, v2 = 0, v3 = 0;
  if (base + 3 < n) {
    int4 v = *(const int4*)(deg + base);
    v0 = v.x; v1 = v.y; v2 = v.z; v3 = v.w;
  } else {
    if (base < n)     v0 = deg[base];
    if (base + 1 < n) v1 = deg[base + 1];
    if (base + 2 < n) v2 = deg[base + 2];
    if (base + 3 < n) v3 = deg[base + 3];
  }
  int s = v0 + v1 + v2 + v3;
  sh[t] = s;
  __syncthreads();
#pragma unroll
  for (int off = 1; off < 256; off <<= 1) {
    int tv = (t >= off) ? sh[t - off] : 0;
    __syncthreads();
    sh[t] += tv;
    __syncthreads();
  }
  int excl = sh[t] - s;
  if (t == 255) bsum[blk] = sh[255];
  if (base < n)     rowptr[base] = excl;
  if (base + 1 < n) rowptr[base + 1] = excl + v0;
  if (base + 2 < n) rowptr[base + 2] = excl + v0 + v1;
  if (base + 3 < n) rowptr[base + 3] = excl + v0 + v1 + v2;
}

#define NBP ((NP + 1023) / 1024)
#define NBA ((NA + 1023) / 1024)

__global__ __launch_bounds__(256)
void scan_blk2(const int* __restrict__ degP, int* __restrict__ rowptrP, int* __restrict__ bsumP,
               const int* __restrict__ degA, int* __restrict__ rowptrA, int* __restrict__ bsumA)
{
  if (blockIdx.x < NBP) scan_blk_body(degP, NP, rowptrP, bsumP, blockIdx.x);
  else                  scan_blk_body(degA, NA, rowptrA, bsumA, blockIdx.x - NBP);
}

__global__ __launch_bounds__(64)
void scan_bsum2(int* __restrict__ bsumP, int* __restrict__ endP,
                int* __restrict__ bsumA, int* __restrict__ endA)
{
  int* bsum = blockIdx.x ? bsumA : bsumP;
  int nb = blockIdx.x ? NBA : NBP;
  int* rpe = blockIdx.x ? endA : endP;
  int t = threadIdx.x;
  int v = (t < nb) ? bsum[t] : 0;
  int inc = v;
#pragma unroll
  for (int off = 1; off < 64; off <<= 1) {
    int o = __shfl_up(inc, off);
    if (t >= off) inc += o;
  }
  if (t < nb) bsum[t] = inc - v;
  if (t == nb - 1) *rpe = inc;
}

__global__ __launch_bounds__(256)
void scan_add2(int* __restrict__ rowptrP, const int* __restrict__ bsumP,
               int* __restrict__ rowptrA, const int* __restrict__ bsumA)
{
  int* rowptr; const int* bsum; int n, blk;
  if (blockIdx.x < NBP) { rowptr = rowptrP; bsum = bsumP; n = NP; blk = blockIdx.x; }
  else                  { rowptr = rowptrA; bsum = bsumA; n = NA; blk = blockIdx.x - NBP; }
  int add = bsum[blk];
  if (add == 0) return;
  int i = blk * 1024 + threadIdx.x * 4;
  if (i < n)     rowptr[i] += add;
  if (i + 1 < n) rowptr[i + 1] += add;
  if (i + 2 < n) rowptr[i + 2] += add;
  if (i + 3 < n) rowptr[i + 3] += add;
}

__global__ __launch_bounds__(256)
void build_scatter3(const int* __restrict__ eiC, const int* __restrict__ eiW,
                    const int* __restrict__ eiB,
                    const int* __restrict__ rowptrP, int* __restrict__ curP,
                    int* __restrict__ srcsP,
                    const int* __restrict__ rowptrA, int* __restrict__ curA,
                    int* __restrict__ srcsA)
{
  int i = blockIdx.x * 256 + threadIdx.x;
  if (i < EC) {
    int src = eiC[i], dst = eiC[EC + i];
    int pos = rowptrP[dst] + atomicAdd(&curP[dst], 1);
    srcsP[pos] = src;
  } else if (i < EC + EW) {
    int e = i - EC;
    int src = eiW[e], dst = eiW[EW + e];
    int pos = rowptrP[dst] + atomicAdd(&curP[dst], 1);
    srcsP[pos] = src | 0x40000000;
  } else if (i < EC + EW + EB) {
    int e = i - EC - EW;
    int src = eiB[e], dst = eiB[EB + e];
    int pos = rowptrA[dst] + atomicAdd(&curA[dst], 1);
    srcsA[pos] = src;
  }
}

// ---------------------------------------------------------------------------
// Merged fused one-pass attention (paper + author). Online softmax w/
// defer-max THR=8 + exact gelu -> bf16. One 64-lane wave per node.
// Edge loop 2-stage software-pipelined (next edge's K/V issued pre-compute).
// ---------------------------------------------------------------------------
__global__ __launch_bounds__(256)
void csr_attn_agg2(const int* __restrict__ rowptrP, const int* __restrict__ srcsP,
                   const int* __restrict__ rowptrA, const int* __restrict__ srcsA,
                   const bf16* __restrict__ qkvP, const bf16* __restrict__ qkvA,
                   const float* __restrict__ prl, float scale,
                   bf16* __restrict__ agP, bf16* __restrict__ agA)
{
  int node = blockIdx.x * 4 + (threadIdx.x >> 6);
  int lane = threadIdx.x & 63;
  int h = lane >> 4;
  const int* rp; const int* srcs;
  const bf16* q; const bf16 *t0, *t1;
  int ld0, off0, ld1, off1;
  float p0, p1;
  bf16* outp;
  if (node < NP) {
    rp = rowptrP; srcs = srcsP;
    q = qkvP + (size_t)node * NQP;
    t0 = qkvP; ld0 = NQP; off0 = 512;
    t1 = qkvA; ld1 = NQA; off1 = 512;
    p0 = prl[h] * scale; p1 = prl[4 + h] * scale;
    outp = agP + (size_t)node * HID;
  } else {
    int r = node - NP;
    if (r >= NA) return;
    rp = rowptrA; srcs = srcsA; node = r;
    q = qkvA + (size_t)r * NQA;
    t0 = qkvP; ld0 = NQP; off0 = 1536;
    t1 = qkvP; ld1 = NQP; off1 = 1536;
    p0 = prl[8 + h] * scale; p1 = p0;
    outp = agA + (size_t)r * HID;
  }
  float qv[8];
  load8b(q, lane, qv);
  int beg = rp[node], end = rp[node + 1];
  float m = -INFINITY, s = 0.f;
  float acc[8] = {};
  float kv[8], vv[8];
  int se = 0;
  if (beg < end) {
    se = srcs[beg];
    int src = se & 0x3FFFFFFF;
    const bf16* row = (se & 0x40000000) ? (t1 + (size_t)src * ld1 + off1)
                                        : (t0 + (size_t)src * ld0 + off0);
    load8b(row, lane, kv);
    load8b(row + 512, lane, vv);
  }
  for (int p = beg; p < end; ++p) {
    bool f1 = (se & 0x40000000) != 0;
    float ckv[8], cvv[8];
#pragma unroll
    for (int i = 0; i < 8; i++) { ckv[i] = kv[i]; cvv[i] = vv[i]; }
    if (p + 1 < end) {
      se = srcs[p + 1];
      int src = se & 0x3FFFFFFF;
      const bf16* row = (se & 0x40000000) ? (t1 + (size_t)src * ld1 + off1)
                                          : (t0 + (size_t)src * ld0 + off0);
      load8b(row, lane, kv);        // issue next-edge loads before compute
      load8b(row + 512, lane, vv);
    }
    float a = 0.f;
#pragma unroll
    for (int i = 0; i < 8; i++) a = fmaf(qv[i], ckv[i], a);
    a += __shfl_xor(a, 1);
    a += __shfl_xor(a, 2);
    a += __shfl_xor(a, 4);
    a += __shfl_xor(a, 8);
    a *= f1 ? p1 : p0;
    if (a > m + 8.f) {              // defer-max (T13)
      float sc = __expf(m - a);
      s *= sc;
#pragma unroll
      for (int i = 0; i < 8; i++) acc[i] *= sc;
      m = a;
    }
    float wgt = __expf(a - m);
    s += wgt;
#pragma unroll
    for (int i = 0; i < 8; i++) acc[i] = fmaf(wgt, cvv[i], acc[i]);
  }
  float inv = 1.f / (s + 1e-16f);
  unsigned short gg[8];
#pragma unroll
  for (int i = 0; i < 8; i++) {
    float v = acc[i] * inv;
    gg[i] = f2bu(0.5f * v * (1.f + erff(v * 0.70710678118654752f)));
  }
  uint4 o;
  o.x = gg[0] | ((unsigned)gg[1] << 16);
  o.y = gg[2] | ((unsigned)gg[3] << 16);
  o.z = gg[4] | ((unsigned)gg[5] << 16);
  o.w = gg[6] | ((unsigned)gg[7] << 16);
  *(uint4*)(outp + lane * 8) = o;
}

// merged skip+residual+LN+relu (paper + author); oplin bf16, h bf16 in/out
__global__ __launch_bounds__(256)
void skip_ln_relu2(const bf16* __restrict__ oplP, const bf16* __restrict__ oplA,
                   bf16* __restrict__ hP, bf16* __restrict__ hA,
                   const float* __restrict__ skip2,
                   const float* __restrict__ g, const float* __restrict__ b)
{
  int row = blockIdx.x;
  const bf16* orow; bf16* hrow; float sk;
  if (row < NP) {
    orow = oplP + (size_t)row * HID; hrow = hP + (size_t)row * HID; sk = skip2[0];
  } else {
    int r = row - NP;
    orow = oplA + (size_t)r * HID; hrow = hA + (size_t)r * HID; sk = skip2[1];
  }
  float sp = 1.f / (1.f + expf(-sk));
  int t = threadIdx.x;
  ushort2 ov = ((const ushort2*)orow)[t];
  ushort2 hv = ((ushort2*)hrow)[t];
  float t0 = sp * bu2f(ov.x) + (2.f - sp) * bu2f(hv.x);
  float t1 = sp * bu2f(ov.y) + (2.f - sp) * bu2f(hv.y);
  float s = t0 + t1, ss = t0 * t0 + t1 * t1;
#pragma unroll
  for (int off = 32; off; off >>= 1) {
    s += __shfl_down(s, off);
    ss += __shfl_down(ss, off);
  }
  __shared__ float sh[8];
  int wid = t >> 6, lane = t & 63;
  if (lane == 0) { sh[wid] = s; sh[4 + wid] = ss; }
  __syncthreads();
  if (t == 0) {
    float S = 0, SS = 0;
    for (int wv = 0; wv < 4; wv++) { S += sh[wv]; SS += sh[4 + wv]; }
    sh[0] = S; sh[4] = SS;
  }
  __syncthreads();
  float mu = sh[0] * (1.f / 512.f);
  float var = sh[4] * (1.f / 512.f) - mu * mu;
  float inv = rsqrtf(var + 1e-5f);
  float y0 = (t0 - mu) * inv * g[2 * t] + b[2 * t];
  float y1 = (t1 - mu) * inv * g[2 * t + 1] + b[2 * t + 1];
  ushort2 o;
  o.x = f2bu(fmaxf(y0, 0.f));
  o.y = f2bu(fmaxf(y1, 0.f));
  ((ushort2*)hrow)[t] = o;
}

// ---------------------------------------------------------------------------
static inline void mgemm2(GemmPair gp, int N0, int N1, hipStream_t s)
{
  gp.nbn0 = N0 / 128;
  gp.nbn1 = N1 / 128;
  int nw0 = ((gp.M0 + 127) / 128) * gp.nbn0;
  int nw1 = ((gp.M1 + 127) / 128) * gp.nbn1;
  gp.nw0 = nw0;
  mfma_gemm2<<<dim3(nw0 + nw1), 256, 0, s>>>(gp);
}

extern "C" void kernel_launch(void* const* d_in, const int* in_sizes, int n_in,
                              void* d_out, int out_size, void* d_ws, size_t ws_size,
                              hipStream_t stream)
{
  const float* x_paper  = (const float*)d_in[0];
  const float* x_author = (const float*)d_in[1];
  const float* Wp_paper = (const float*)d_in[2];
  const float* bp_paper = (const float*)d_in[3];
  const float* Wp_author= (const float*)d_in[4];
  const float* bp_author= (const float*)d_in[5];
  const float* Wk = (const float*)d_in[6];
  const float* bk = (const float*)d_in[7];
  const float* Wq = (const float*)d_in[8];
  const float* bq = (const float*)d_in[9];
  const float* Wv = (const float*)d_in[10];
  const float* bv = (const float*)d_in[11];
  const float* Wa = (const float*)d_in[12];
  const float* ba = (const float*)d_in[13];
  const float* skip = (const float*)d_in[14];
  const float* a_rel = (const float*)d_in[15];
  const float* m_rel = (const float*)d_in[16];
  const float* p_rel = (const float*)d_in[17];
  const float* ln_g = (const float*)d_in[18];
  const float* ln_b = (const float*)d_in[19];
  const float* W256 = (const float*)d_in[20];
  const float* b256 = (const float*)d_in[21];
  const float* W128 = (const float*)d_in[22];
  const float* b128 = (const float*)d_in[23];
  const int* ei_c = (const int*)d_in[24];
  const int* ei_w = (const int*)d_in[25];
  const int* ei_b = (const int*)d_in[26];
  float* out = (float*)d_out;

  const size_t NPe = (size_t)NP * HID, NAe = (size_t)NA * HID;
  const size_t HH = (size_t)HID * HID;
  char* w = (char*)d_ws;
  size_t off = 0;
  auto alloc = [&](size_t bytes) -> void* {
    void* p = (void*)(w + off);
    off += (bytes + 255) & ~(size_t)255;
    return p;
  };
  bf16* hb_p  = (bf16*)alloc(NPe * 2);
  bf16* hb_a  = (bf16*)alloc(NAe * 2);
  bf16* qkv_p = (bf16*)alloc((size_t)NP * NQP * 2);
  bf16* qkv_a = (bf16*)alloc((size_t)NA * NQA * 2);
  bf16* ag_p  = (bf16*)alloc(NPe * 2);
  bf16* ag_a  = (bf16*)alloc(NAe * 2);
  float* Wf32 = (float*)alloc(12 * HH * 4);
  bf16* WBtP  = (bf16*)alloc((size_t)2 * NQP * HID * 2);
  bf16* WBtA  = (bf16*)alloc((size_t)2 * NQA * HID * 2);
  float* pbP  = (float*)alloc((size_t)2 * NQP * 4);
  float* pbA  = (float*)alloc((size_t)2 * NQA * 4);
  bf16* WaT   = (bf16*)alloc(4 * HH * 2);
  bf16* W256T = (bf16*)alloc((size_t)HID * 256 * 2);
  bf16* W128T = (bf16*)alloc((size_t)256 * 128 * 2);
  bf16* WpTp  = (bf16*)alloc((size_t)INDIM * HID * 2);
  bf16* WpTa  = (bf16*)alloc((size_t)INDIM * HID * 2);
  int* rowptrP = (int*)alloc((size_t)(NP + 1) * 4);
  int* rowptrA = (int*)alloc((size_t)(NA + 1) * 4);
  int* degP    = (int*)alloc((size_t)(2 * NP + 2 * NA) * 4);  // degP|degA|curP|curA
  int* degA    = degP + NP;
  int* curP    = degA + NA;
  int* curA    = curP + NP;
  int* srcsP   = (int*)alloc((size_t)(EC + EW) * 4);
  int* srcsA   = (int*)alloc((size_t)EB * 4);
  int* bsumP   = (int*)alloc(64 * 4);
  int* bsumA   = (int*)alloc(64 * 4);
  if (off > ws_size) return;

  const float scale = 0.08838834764831845f;  // 1/sqrt(128)

  // --- CSR build (merged launches) ---
  (void)hipMemsetAsync(degP, 0, (size_t)(2 * NP + 2 * NA) * 4, stream);
  build_hist3<<<dim3((EC + EW + EB + 255) / 256), 256, 0, stream>>>(ei_c, ei_w, ei_b, degP, degA);
  scan_blk2<<<dim3(NBP + NBA), 256, 0, stream>>>(degP, rowptrP, bsumP, degA, rowptrA, bsumA);
  scan_bsum2<<<dim3(2), 64, 0, stream>>>(bsumP, rowptrP + NP, bsumA, rowptrA + NA);
  scan_add2<<<dim3(NBP + NBA), 256, 0, stream>>>(rowptrP, bsumP, rowptrA, bsumA);
  build_scatter3<<<dim3((EC + EW + EB + 255) / 256), 256, 0, stream>>>(
      ei_c, ei_w, ei_b, rowptrP, curP, srcsP, rowptrA, curA, srcsA);

  // --- fused relation weights + layer packs ---
  FuseArgs fa;
  TrArgs ta;
  CopyB cb;
  for (int l = 0; l < NLAY; l++) {
    bf16* packP = WBtP + (size_t)l * NQP * HID;
    bf16* packA = WBtA + (size_t)l * NQA * HID;
    float* pbPl = pbP + (size_t)l * NQP;
    float* pbAl = pbA + (size_t)l * NQA;
    for (int r = 0; r < 3; r++)
      for (int s = 0; s < 2; s++) {
        int c = (l * 3 + r) * 2 + s;
        int t = (r == 1) ? 1 : 0;
        fa.W[c]   = (s == 0 ? Wk : Wv) + (size_t)(l * 2 + t) * HH;
        fa.rel[c] = (s == 0 ? a_rel : m_rel) + (size_t)(l * 3 + r) * NHEAD * DH * DH;
        fa.bin[c] = (s == 0 ? bk : bv) + (size_t)(l * 2 + t) * HID;
        fa.out[c] = Wf32 + (size_t)c * HH;
        ta.src[c] = fa.out[c];
        if (r == 0) {
          ta.dst[c]  = packP + (size_t)(512 + s * 512) * HID;
          fa.bout[c] = pbPl + 512 + s * 512;
        } else if (r == 1) {
          ta.dst[c]  = packA + (size_t)(512 + s * 512) * HID;
          fa.bout[c] = pbAl + 512 + s * 512;
        } else {
          ta.dst[c]  = packP + (size_t)(1536 + s * 512) * HID;
          fa.bout[c] = pbPl + 1536 + s * 512;
        }
      }
    ta.src[12 + l * 2 + 0] = Wq + (size_t)(l * 2 + 0) * HH;
    ta.dst[12 + l * 2 + 0] = packP;
    ta.src[12 + l * 2 + 1] = Wq + (size_t)(l * 2 + 1) * HH;
    ta.dst[12 + l * 2 + 1] = packA;
    ta.src[16 + l * 2 + 0] = Wa + (size_t)(l * 2 + 0) * HH;
    ta.dst[16 + l * 2 + 0] = WaT + (size_t)(l * 2 + 0) * HH;
    ta.src[16 + l * 2 + 1] = Wa + (size_t)(l * 2 + 1) * HH;
    ta.dst[16 + l * 2 + 1] = WaT + (size_t)(l * 2 + 1) * HH;
    cb.src[l * 2 + 0] = bq + (size_t)(l * 2 + 0) * HID;
    cb.dst[l * 2 + 0] = pbPl;
    cb.src[l * 2 + 1] = bq + (size_t)(l * 2 + 1) * HID;
    cb.dst[l * 2 + 1] = pbAl;
  }
  gemm_fuse<<<dim3(8, 2, 48), 256, 0, stream>>>(fa);
  transpose20<<<dim3(16, 16, 20), dim3(32, 8), 0, stream>>>(ta);
  bias_fuse_all<<<dim3(12), 512, 0, stream>>>(fa);
  copy_bias<<<dim3(4), 512, 0, stream>>>(cb);
  {
    dim3 b(32, 8);
    transpose_to_bf16<<<dim3(8, 16), b, 0, stream>>>(W256, W256T, HID, 256);
    transpose_to_bf16<<<dim3(4, 8), b, 0, stream>>>(W128, W128T, 256, 128);
    transpose_to_bf16<<<dim3(16, 24), b, 0, stream>>>(Wp_paper, WpTp, INDIM, HID);
    transpose_to_bf16<<<dim3(16, 24), b, 0, stream>>>(Wp_author, WpTa, INDIM, HID);
  }

  // --- input conversion + projection ---
  bf16* xb_p = qkv_p;
  bf16* xb_a = qkv_a;
  long long nxp = (long long)NP * INDIM, nxa = (long long)NA * INDIM;
  f32_to_bf16_2<<<dim3((int)(((nxp + nxa) / 4 + 255) / 256)), 256, 0, stream>>>(
      x_paper, xb_p, nxp, x_author, xb_a, nxa);
  {
    GemmPair gp{};
    gp.A0 = xb_p; gp.lda0 = INDIM; gp.B0 = WpTp; gp.ldb0 = INDIM;
    gp.b0 = bp_paper; gp.C0 = hb_p; gp.ldc0 = HID;
    gp.M0 = NP; gp.K0 = INDIM; gp.act0 = 0; gp.bf0 = 1;
    gp.A1 = xb_a; gp.lda1 = INDIM; gp.B1 = WpTa; gp.ldb1 = INDIM;
    gp.b1 = bp_author; gp.C1 = hb_a; gp.ldc1 = HID;
    gp.M1 = NA; gp.K1 = INDIM; gp.act1 = 0; gp.bf1 = 1;
    mgemm2(gp, HID, HID, stream);
  }

  for (int l = 0; l < NLAY; l++) {
    const float* prl = p_rel + (size_t)l * 3 * NHEAD;
    const bf16* packP = WBtP + (size_t)l * NQP * HID;
    const bf16* packA = WBtA + (size_t)l * NQA * HID;
    const float* pbPl = pbP + (size_t)l * NQP;
    const float* pbAl = pbA + (size_t)l * NQA;

    // fused projections pair: q|kv0|kv2 (paper) + q|kv1 (author)
    {
      GemmPair gp{};
      gp.A0 = hb_p; gp.lda0 = HID; gp.B0 = packP; gp.ldb0 = HID;
      gp.b0 = pbPl; gp.C0 = qkv_p; gp.ldc0 = NQP;
      gp.M0 = NP; gp.K0 = HID; gp.act0 = 0; gp.bf0 = 1;
      gp.A1 = hb_a; gp.lda1 = HID; gp.B1 = packA; gp.ldb1 = HID;
      gp.b1 = pbAl; gp.C1 = qkv_a; gp.ldc1 = NQA;
      gp.M1 = NA; gp.K1 = HID; gp.act1 = 0; gp.bf1 = 1;
      mgemm2(gp, NQP, NQA, stream);
    }
    // merged one-pass attention + gelu
    csr_attn_agg2<<<dim3((NP + NA + 3) / 4), 256, 0, stream>>>(
        rowptrP, srcsP, rowptrA, srcsA, qkv_p, qkv_a, prl, scale, ag_p, ag_a);
    // output linear pair (bf16 out into dead qkv slabs)
    bf16* opl_p = qkv_p;
    bf16* opl_a = qkv_a;
    {
      GemmPair gp{};
      gp.A0 = ag_p; gp.lda0 = HID; gp.B0 = WaT + (size_t)(l * 2 + 0) * HH; gp.ldb0 = HID;
      gp.b0 = ba + (size_t)(l * 2 + 0) * HID; gp.C0 = opl_p; gp.ldc0 = HID;
      gp.M0 = NP; gp.K0 = HID; gp.act0 = 0; gp.bf0 = 1;
      gp.A1 = ag_a; gp.lda1 = HID; gp.B1 = WaT + (size_t)(l * 2 + 1) * HH; gp.ldb1 = HID;
      gp.b1 = ba + (size_t)(l * 2 + 1) * HID; gp.C1 = opl_a; gp.ldc1 = HID;
      gp.M1 = NA; gp.K1 = HID; gp.act1 = 0; gp.bf1 = 1;
      mgemm2(gp, HID, HID, stream);
    }
    // merged skip + residual + LN + relu
    skip_ln_relu2<<<dim3(NP + NA), 256, 0, stream>>>(
        opl_p, opl_a, hb_p, hb_a, skip + l * 2,
        ln_g + (size_t)l * HID, ln_b + (size_t)l * HID);
  }

  // final MLP
  bf16* h256_p = ag_p;
  bf16* h256_a = ag_a;
  {
    GemmPair gp{};
    gp.A0 = hb_p; gp.lda0 = HID; gp.B0 = W256T; gp.ldb0 = HID;
    gp.b0 = b256; gp.C0 = h256_p; gp.ldc0 = 256;
    gp.M0 = NP; gp.K0 = HID; gp.act0 = 1; gp.bf0 = 1;
    gp.A1 = hb_a; gp.lda1 = HID; gp.B1 = W256T; gp.ldb1 = HID;
    gp.b1 = b256; gp.C1 = h256_a; gp.ldc1 = 256;
    gp.M1 = NA; gp.K1 = HID; gp.act1 = 1; gp.bf1 = 1;
    mgemm2(gp, 256, 256, stream);
  }
  {
    GemmPair gp{};
    gp.A0 = h256_p; gp.lda0 = 256; gp.B0 = W128T; gp.ldb0 = 256;
    gp.b0 = b128; gp.C0 = out; gp.ldc0 = 128;
    gp.M0 = NP; gp.K0 = 256; gp.act0 = 0; gp.bf0 = 0;
    gp.A1 = h256_a; gp.lda1 = 256; gp.B1 = W128T; gp.ldb1 = 256;
    gp.b1 = b128; gp.C1 = out + (size_t)NP * 128; gp.ldc1 = 128;
    gp.M1 = NA; gp.K1 = 256; gp.act1 = 0; gp.bf1 = 0;
    mgemm2(gp, 128, 128, stream);
  }
}

// Round 17
// 816.846 us; speedup vs baseline: 1.0920x; 1.0362x over previous
//
#include <hip/hip_runtime.h>
#include <hip/hip_bf16.h>
#include <math.h>

#define NHEAD 4
#define DH 128
#define HID 512
#define NLAY 2
#define NP 30000
#define NA 10000
#define INDIM 768
#define EC 150000
#define EW 80000
#define EB 80000
#define NQP 2560   // q | kv0 | kv2
#define NQA 1536   // q | kv1

typedef __hip_bfloat16 bf16;
typedef __attribute__((ext_vector_type(8))) short bf16x8;
typedef __attribute__((ext_vector_type(4))) float f32x4;
typedef __attribute__((ext_vector_type(4))) unsigned int u32x4;

__device__ __forceinline__ unsigned short f2bu(float f){ bf16 t = __float2bfloat16(f); return *(unsigned short*)&t; }
__device__ __forceinline__ float bu2f(unsigned short u){ return __uint_as_float((unsigned)u << 16); }

__device__ __forceinline__ void load8b(const bf16* __restrict__ p, int i8, float* o){
  uint4 r = ((const uint4*)p)[i8];
  o[0]=__uint_as_float(r.x<<16); o[1]=__uint_as_float(r.x&0xffff0000u);
  o[2]=__uint_as_float(r.y<<16); o[3]=__uint_as_float(r.y&0xffff0000u);
  o[4]=__uint_as_float(r.z<<16); o[5]=__uint_as_float(r.z&0xffff0000u);
  o[6]=__uint_as_float(r.w<<16); o[7]=__uint_as_float(r.w&0xffff0000u);
}

// async global->LDS, 16B per lane, wave-uniform LDS base + lane*16
__device__ __forceinline__ void gload16(const void* g, void* l) {
  __builtin_amdgcn_global_load_lds((const __attribute__((address_space(1))) void*)g,
                                   (__attribute__((address_space(3))) void*)l, 16, 0, 0);
}

// ---------------------------------------------------------------------------
// Paired MFMA bf16 GEMM (round-12 structure + occupancy cap): two sub-GEMMs
// in ONE launch. 128x128 tile, BK=64, single-buffered 33.8KB LDS.
// __launch_bounds__(256,4): cap total regs/wave at 128 (64 acc + 64 arch) ->
// 4 waves/SIMD instead of 3 (total was ~144 = 80 arch + 64 acc; r15 showed
// LDS is NOT the occupancy gate -- VGPRs are).
// bf16 C: full-tile LDS-bounce epilogue -> 16B/lane NT stores. fp32 C: NT.
// ---------------------------------------------------------------------------
struct GemmPair {
  const bf16 *A0, *A1, *B0, *B1;
  const float *b0, *b1;
  void *C0, *C1;
  int lda0, lda1, ldb0, ldb1, ldc0, ldc1;
  int M0, M1, K0, K1;
  int act0, act1, bf0, bf1;      // bfX: 1 = bf16 C, 0 = fp32 C
  int nbn0, nbn1, nw0;
};

#define TSTRIDE 132   // padded bf16 epilogue stride

__global__ __launch_bounds__(256, 4)
void mfma_gemm2(GemmPair gp)
{
  __shared__ __align__(16) short smem[128 * TSTRIDE];  // 33.8 KB
  const int tid = threadIdx.x;
  const int lane = tid & 63, w = tid >> 6;
  const int nwg = gridDim.x;
  const int bid = blockIdx.x;
  const int xcd = bid & 7, pos = bid >> 3;
  const int q8 = nwg >> 3, r8 = nwg & 7;
  const int work = (xcd < r8 ? xcd * (q8 + 1) : r8 * (q8 + 1) + (xcd - r8) * q8) + pos;
  const int g = work >= gp.nw0;
  const int w2 = g ? work - gp.nw0 : work;
  const bf16* A  = g ? gp.A1 : gp.A0;
  const bf16* Bt = g ? gp.B1 : gp.B0;
  const float* bias = g ? gp.b1 : gp.b0;
  void* Cv = g ? gp.C1 : gp.C0;
  const int lda = g ? gp.lda1 : gp.lda0;
  const int ldb = g ? gp.ldb1 : gp.ldb0;
  const int ldc = g ? gp.ldc1 : gp.ldc0;
  const int M = g ? gp.M1 : gp.M0;
  const int K = g ? gp.K1 : gp.K0;
  const int act = g ? gp.act1 : gp.act0;
  const int isbf = g ? gp.bf1 : gp.bf0;
  const int nbn = g ? gp.nbn1 : gp.nbn0;
  const int brow = (w2 / nbn) * 128, bcol = (w2 % nbn) * 128;
  const int wr = w >> 1, wc = w & 1;

  f32x4 acc[4][4];
#pragma unroll
  for (int m = 0; m < 4; m++)
#pragma unroll
    for (int n = 0; n < 4; n++) acc[m][n] = (f32x4){0.f, 0.f, 0.f, 0.f};

  short* Asb = smem;
  short* Bsb = smem + 8192;
  const int nk = K >> 6;
  for (int t = 0; t < nk; t++) {
    const int k0 = t << 6;
#pragma unroll
    for (int i = 0; i < 4; i++) {
      int chunk = i * 4 + w;                   // wave-uniform
      int c_lin = chunk * 64 + lane;
      int row = c_lin >> 3;
      int kc = ((c_lin & 7) ^ (row & 7)) * 8;  // inverse-swizzled source k
      int growA = brow + row; growA = growA < M ? growA : M - 1;
      gload16(A + (size_t)growA * lda + k0 + kc, Asb + chunk * 512);
      gload16(Bt + (size_t)(bcol + row) * ldb + k0 + kc, Bsb + chunk * 512);
    }
    __syncthreads();   // drains vmcnt: staged tile visible
#pragma unroll
    for (int kk = 0; kk < 2; kk++) {
      const int ke = kk * 32 + (lane >> 4) * 8;
      bf16x8 af[4], bq[4];
#pragma unroll
      for (int m = 0; m < 4; m++) {
        int row = wr * 64 + m * 16 + (lane & 15);
        af[m] = *(const bf16x8*)(Asb + row * 64 + (ke ^ ((row & 7) << 3)));
      }
#pragma unroll
      for (int n = 0; n < 4; n++) {
        int col = wc * 64 + n * 16 + (lane & 15);
        bq[n] = *(const bf16x8*)(Bsb + col * 64 + (ke ^ ((col & 7) << 3)));
      }
#pragma unroll
      for (int m = 0; m < 4; m++)
#pragma unroll
        for (int n = 0; n < 4; n++)
          acc[m][n] = __builtin_amdgcn_mfma_f32_16x16x32_bf16(af[m], bq[n], acc[m][n], 0, 0, 0);
    }
    __syncthreads();   // all waves done reading before next stage overwrites
  }

  if (isbf) {
    // ---- LDS-bounce epilogue ----
#pragma unroll
    for (int m = 0; m < 4; m++) {
      int row0 = wr * 64 + m * 16 + (lane >> 4) * 4;
#pragma unroll
      for (int n = 0; n < 4; n++) {
        int col = wc * 64 + n * 16 + (lane & 15);
        float bv = bias ? bias[bcol + col] : 0.f;
#pragma unroll
        for (int r = 0; r < 4; r++) {
          float v = acc[m][n][r] + bv;
          if (act) v = fmaxf(v, 0.f);
          smem[(row0 + r) * TSTRIDE + col] = (short)f2bu(v);
        }
      }
    }
    __syncthreads();
#pragma unroll
    for (int it = 0; it < 8; it++) {
      int chunk = it * 256 + tid;        // 0..2047 : 128 rows x 16 chunks of 16B
      int row = chunk >> 4, c16 = chunk & 15;
      int gr = brow + row;
      if (gr < M) {
        u32x4 v = *(const u32x4*)(smem + row * TSTRIDE + c16 * 8);
        __builtin_nontemporal_store(v,
            (u32x4*)((unsigned short*)Cv + (size_t)gr * ldc + bcol + c16 * 8));
      }
    }
  } else {
    // fp32 C: direct NT (16 lanes x 4B = full 64B line)
#pragma unroll
    for (int m = 0; m < 4; m++) {
      int gr0 = brow + wr * 64 + m * 16 + (lane >> 4) * 4;
#pragma unroll
      for (int n = 0; n < 4; n++) {
        int gc = bcol + wc * 64 + n * 16 + (lane & 15);
        float bv = bias ? bias[gc] : 0.f;
#pragma unroll
        for (int r = 0; r < 4; r++) {
          int gr = gr0 + r;
          if (gr < M) {
            float v = acc[m][n][r] + bv;
            if (act) v = fmaxf(v, 0.f);
            __builtin_nontemporal_store(v, (float*)Cv + (size_t)gr * ldc + gc);
          }
        }
      }
    }
  }
}

// ---------------------------------------------------------------------------
// Weight preparation
// ---------------------------------------------------------------------------
struct FuseArgs {
  const float* W[12];
  const float* rel[12];
  const float* bin[12];
  float* out[12];
  float* bout[12];
};
struct TrArgs {
  const float* src[20];
  bf16* dst[20];
};
struct CopyB { const float* src[4]; float* dst[4]; };

__global__ __launch_bounds__(256)
void gemm_fuse(FuseArgs fa)
{
  int c = blockIdx.z >> 2, h = blockIdx.z & 3;
  const float* A = fa.W[c] + h * 128;
  const float* B = fa.rel[c] + (size_t)h * 128 * 128;
  float* C = fa.out[c] + h * 128;
  __shared__ float Ast[64][17];
  __shared__ float Bst[16][64];
  const int tid = threadIdx.x;
  const int tx = tid & 15, ty = tid >> 4;
  const int bm = blockIdx.x * 64, bn = blockIdx.y * 64;
  float acc[4][4] = {};
  for (int k0 = 0; k0 < 128; k0 += 16) {
#pragma unroll
    for (int i = 0; i < 4; i++) {
      int lin = tid + i * 256;
      int m = lin >> 4, kk = lin & 15;
      Ast[m][kk] = A[(size_t)(bm + m) * 512 + k0 + kk];
      int kb = lin >> 6, nb = lin & 63;
      Bst[kb][nb] = B[(size_t)(k0 + kb) * 128 + bn + nb];
    }
    __syncthreads();
#pragma unroll
    for (int kk = 0; kk < 16; kk++) {
      float a[4], b[4];
#pragma unroll
      for (int i = 0; i < 4; i++) a[i] = Ast[ty * 4 + i][kk];
#pragma unroll
      for (int j = 0; j < 4; j++) b[j] = Bst[kk][tx * 4 + j];
#pragma unroll
      for (int i = 0; i < 4; i++)
#pragma unroll
        for (int j = 0; j < 4; j++)
          acc[i][j] = fmaf(a[i], b[j], acc[i][j]);
    }
    __syncthreads();
  }
#pragma unroll
  for (int i = 0; i < 4; i++)
#pragma unroll
    for (int j = 0; j < 4; j++)
      C[(size_t)(bm + ty * 4 + i) * 512 + bn + tx * 4 + j] = acc[i][j];
}

__global__ __launch_bounds__(256)
void transpose20(TrArgs ta)
{
  int c = blockIdx.z;
  const float* in = ta.src[c];
  bf16* o = ta.dst[c];
  __shared__ float t[32][33];
  int bn = blockIdx.x * 32, bk = blockIdx.y * 32;
  int x = threadIdx.x, y = threadIdx.y;
#pragma unroll
  for (int i = 0; i < 32; i += 8)
    t[y + i][x] = in[(size_t)(bk + y + i) * 512 + bn + x];
  __syncthreads();
#pragma unroll
  for (int i = 0; i < 32; i += 8)
    o[(size_t)(bn + y + i) * 512 + bk + x] = __float2bfloat16(t[x][y + i]);
}

__global__ __launch_bounds__(512)
void bias_fuse_all(FuseArgs fa)
{
  int c = blockIdx.x;
  int j = threadIdx.x;
  int h = j >> 7, e = j & 127;
  const float* bh = fa.bin[c] + h * DH;
  const float* rh = fa.rel[c] + (size_t)h * DH * DH;
  float s = 0.f;
  for (int d = 0; d < DH; d++) s = fmaf(bh[d], rh[d * DH + e], s);
  fa.bout[c][j] = s;
}

__global__ __launch_bounds__(512)
void copy_bias(CopyB cb)
{
  cb.dst[blockIdx.x][threadIdx.x] = cb.src[blockIdx.x][threadIdx.x];
}

__global__ __launch_bounds__(256)
void transpose_to_bf16(const float* __restrict__ in, bf16* __restrict__ out,
                       int K_, int N_)
{
  __shared__ float t[32][33];
  int bn = blockIdx.x * 32, bk = blockIdx.y * 32;
  int x = threadIdx.x, y = threadIdx.y;
#pragma unroll
  for (int i = 0; i < 32; i += 8) {
    int k = bk + y + i, n = bn + x;
    if (k < K_ && n < N_) t[y + i][x] = in[(size_t)k * N_ + n];
  }
  __syncthreads();
#pragma unroll
  for (int i = 0; i < 32; i += 8) {
    int n = bn + y + i, k = bk + x;
    if (n < N_ && k < K_) out[(size_t)n * K_ + k] = __float2bfloat16(t[x][y + i]);
  }
}

__global__ __launch_bounds__(256)
void f32_to_bf16_2(const float* __restrict__ s0, bf16* __restrict__ d0, long long n0,
                   const float* __restrict__ s1, bf16* __restrict__ d1, long long n1)
{
  long long i = ((long long)blockIdx.x * 256 + threadIdx.x) * 4;
  const float* s; bf16* d;
  if (i < n0) { s = s0; d = d0; }
  else { i -= n0; if (i >= n1) return; s = s1; d = d1; }
  float4 v = *(const float4*)(s + i);
  ushort4 o;
  o.x = f2bu(v.x); o.y = f2bu(v.y); o.z = f2bu(v.z); o.w = f2bu(v.w);
  *(ushort4*)(d + i) = o;
}

// ---------------------------------------------------------------------------
// CSR build (merged launches)
// ---------------------------------------------------------------------------
__global__ __launch_bounds__(256)
void build_hist3(const int* __restrict__ eiC, const int* __restrict__ eiW,
                 const int* __restrict__ eiB,
                 int* __restrict__ degP, int* __restrict__ degA)
{
  int i = blockIdx.x * 256 + threadIdx.x;
  if (i < EC) atomicAdd(&degP[eiC[EC + i]], 1);
  else if (i < EC + EW) atomicAdd(&degP[eiW[EW + (i - EC)]], 1);
  else if (i < EC + EW + EB) atomicAdd(&degA[eiB[EB + (i - EC - EW)]], 1);
}

__device__ __forceinline__ void scan_blk_body(const int* __restrict__ deg, int n,
                                              int* __restrict__ rowptr,
                                              int* __restrict__ bsum, int blk)
{
  __shared__ int sh[256];
  int t = threadIdx.x;
  int base = blk * 1024 + t * 4;
  int v0 = 0, v1 = 0, v2 = 0, v3 = 0;
  if (base + 3 < n) {
    int4 v = *(const int4*)(deg + base);
    v0 = v.x; v1 = v.y; v2 = v.z; v3 = v.w;
  } else {
    if (base < n)     v0 = deg[base];
    if (base + 1 < n) v1 = deg[base + 1];
    if (base + 2 < n) v2 = deg[base + 2];
    if (base + 3 < n) v3 = deg[base + 3];
  }
  int s = v0 + v1 + v2 + v3;
  sh[t] = s;
  __syncthreads();
#pragma unroll
  for (int off = 1; off < 256; off <<= 1) {
    int tv = (t >= off) ? sh[t - off] : 0;
    __syncthreads();
    sh[t] += tv;
    __syncthreads();
  }
  int excl = sh[t] - s;
  if (t == 255) bsum[blk] = sh[255];
  if (base < n)     rowptr[base] = excl;
  if (base + 1 < n) rowptr[base + 1] = excl + v0;
  if (base + 2 < n) rowptr[base + 2] = excl + v0 + v1;
  if (base + 3 < n) rowptr[base + 3] = excl + v0 + v1 + v2;
}

#define NBP ((NP + 1023) / 1024)
#define NBA ((NA + 1023) / 1024)

__global__ __launch_bounds__(256)
void scan_blk2(const int* __restrict__ degP, int* __restrict__ rowptrP, int* __restrict__ bsumP,
               const int* __restrict__ degA, int* __restrict__ rowptrA, int* __restrict__ bsumA)
{
  if (blockIdx.x < NBP) scan_blk_body(degP, NP, rowptrP, bsumP, blockIdx.x);
  else                  scan_blk_body(degA, NA, rowptrA, bsumA, blockIdx.x - NBP);
}

__global__ __launch_bounds__(64)
void scan_bsum2(int* __restrict__ bsumP, int* __restrict__ endP,
                int* __restrict__ bsumA, int* __restrict__ endA)
{
  int* bsum = blockIdx.x ? bsumA : bsumP;
  int nb = blockIdx.x ? NBA : NBP;
  int* rpe = blockIdx.x ? endA : endP;
  int t = threadIdx.x;
  int v = (t < nb) ? bsum[t] : 0;
  int inc = v;
#pragma unroll
  for (int off = 1; off < 64; off <<= 1) {
    int o = __shfl_up(inc, off);
    if (t >= off) inc += o;
  }
  if (t < nb) bsum[t] = inc - v;
  if (t == nb - 1) *rpe = inc;
}

__global__ __launch_bounds__(256)
void scan_add2(int* __restrict__ rowptrP, const int* __restrict__ bsumP,
               int* __restrict__ rowptrA, const int* __restrict__ bsumA)
{
  int* rowptr; const int* bsum; int n, blk;
  if (blockIdx.x < NBP) { rowptr = rowptrP; bsum = bsumP; n = NP; blk = blockIdx.x; }
  else                  { rowptr = rowptrA; bsum = bsumA; n = NA; blk = blockIdx.x - NBP; }
  int add = bsum[blk];
  if (add == 0) return;
  int i = blk * 1024 + threadIdx.x * 4;
  if (i < n)     rowptr[i] += add;
  if (i + 1 < n) rowptr[i + 1] += add;
  if (i + 2 < n) rowptr[i + 2] += add;
  if (i + 3 < n) rowptr[i + 3] += add;
}

__global__ __launch_bounds__(256)
void build_scatter3(const int* __restrict__ eiC, const int* __restrict__ eiW,
                    const int* __restrict__ eiB,
                    const int* __restrict__ rowptrP, int* __restrict__ curP,
                    int* __restrict__ srcsP,
                    const int* __restrict__ rowptrA, int* __restrict__ curA,
                    int* __restrict__ srcsA)
{
  int i = blockIdx.x * 256 + threadIdx.x;
  if (i < EC) {
    int src = eiC[i], dst = eiC[EC + i];
    int pos = rowptrP[dst] + atomicAdd(&curP[dst], 1);
    srcsP[pos] = src;
  } else if (i < EC + EW) {
    int e = i - EC;
    int src = eiW[e], dst = eiW[EW + e];
    int pos = rowptrP[dst] + atomicAdd(&curP[dst], 1);
    srcsP[pos] = src | 0x40000000;
  } else if (i < EC + EW + EB) {
    int e = i - EC - EW;
    int src = eiB[e], dst = eiB[EB + e];
    int pos = rowptrA[dst] + atomicAdd(&curA[dst], 1);
    srcsA[pos] = src;
  }
}

// ---------------------------------------------------------------------------
// Merged fused one-pass attention (paper + author). Online softmax w/
// defer-max THR=8 + exact gelu -> bf16. One 64-lane wave per node.
// Edge loop 2-stage software-pipelined (next edge's K/V issued pre-compute).
// ---------------------------------------------------------------------------
__global__ __launch_bounds__(256)
void csr_attn_agg2(const int* __restrict__ rowptrP, const int* __restrict__ srcsP,
                   const int* __restrict__ rowptrA, const int* __restrict__ srcsA,
                   const bf16* __restrict__ qkvP, const bf16* __restrict__ qkvA,
                   const float* __restrict__ prl, float scale,
                   bf16* __restrict__ agP, bf16* __restrict__ agA)
{
  int node = blockIdx.x * 4 + (threadIdx.x >> 6);
  int lane = threadIdx.x & 63;
  int h = lane >> 4;
  const int* rp; const int* srcs;
  const bf16* q; const bf16 *t0, *t1;
  int ld0, off0, ld1, off1;
  float p0, p1;
  bf16* outp;
  if (node < NP) {
    rp = rowptrP; srcs = srcsP;
    q = qkvP + (size_t)node * NQP;
    t0 = qkvP; ld0 = NQP; off0 = 512;
    t1 = qkvA; ld1 = NQA; off1 = 512;
    p0 = prl[h] * scale; p1 = prl[4 + h] * scale;
    outp = agP + (size_t)node * HID;
  } else {
    int r = node - NP;
    if (r >= NA) return;
    rp = rowptrA; srcs = srcsA; node = r;
    q = qkvA + (size_t)r * NQA;
    t0 = qkvP; ld0 = NQP; off0 = 1536;
    t1 = qkvP; ld1 = NQP; off1 = 1536;
    p0 = prl[8 + h] * scale; p1 = p0;
    outp = agA + (size_t)r * HID;
  }
  float qv[8];
  load8b(q, lane, qv);
  int beg = rp[node], end = rp[node + 1];
  float m = -INFINITY, s = 0.f;
  float acc[8] = {};
  float kv[8], vv[8];
  int se = 0;
  if (beg < end) {
    se = srcs[beg];
    int src = se & 0x3FFFFFFF;
    const bf16* row = (se & 0x40000000) ? (t1 + (size_t)src * ld1 + off1)
                                        : (t0 + (size_t)src * ld0 + off0);
    load8b(row, lane, kv);
    load8b(row + 512, lane, vv);
  }
  for (int p = beg; p < end; ++p) {
    bool f1 = (se & 0x40000000) != 0;
    float ckv[8], cvv[8];
#pragma unroll
    for (int i = 0; i < 8; i++) { ckv[i] = kv[i]; cvv[i] = vv[i]; }
    if (p + 1 < end) {
      se = srcs[p + 1];
      int src = se & 0x3FFFFFFF;
      const bf16* row = (se & 0x40000000) ? (t1 + (size_t)src * ld1 + off1)
                                          : (t0 + (size_t)src * ld0 + off0);
      load8b(row, lane, kv);        // issue next-edge loads before compute
      load8b(row + 512, lane, vv);
    }
    float a = 0.f;
#pragma unroll
    for (int i = 0; i < 8; i++) a = fmaf(qv[i], ckv[i], a);
    a += __shfl_xor(a, 1);
    a += __shfl_xor(a, 2);
    a += __shfl_xor(a, 4);
    a += __shfl_xor(a, 8);
    a *= f1 ? p1 : p0;
    if (a > m + 8.f) {              // defer-max (T13)
      float sc = __expf(m - a);
      s *= sc;
#pragma unroll
      for (int i = 0; i < 8; i++) acc[i] *= sc;
      m = a;
    }
    float wgt = __expf(a - m);
    s += wgt;
#pragma unroll
    for (int i = 0; i < 8; i++) acc[i] = fmaf(wgt, cvv[i], acc[i]);
  }
  float inv = 1.f / (s + 1e-16f);
  unsigned short gg[8];
#pragma unroll
  for (int i = 0; i < 8; i++) {
    float v = acc[i] * inv;
    gg[i] = f2bu(0.5f * v * (1.f + erff(v * 0.70710678118654752f)));
  }
  uint4 o;
  o.x = gg[0] | ((unsigned)gg[1] << 16);
  o.y = gg[2] | ((unsigned)gg[3] << 16);
  o.z = gg[4] | ((unsigned)gg[5] << 16);
  o.w = gg[6] | ((unsigned)gg[7] << 16);
  *(uint4*)(outp + lane * 8) = o;
}

// merged skip+residual+LN+relu (paper + author); oplin bf16, h bf16 in/out
__global__ __launch_bounds__(256)
void skip_ln_relu2(const bf16* __restrict__ oplP, const bf16* __restrict__ oplA,
                   bf16* __restrict__ hP, bf16* __restrict__ hA,
                   const float* __restrict__ skip2,
                   const float* __restrict__ g, const float* __restrict__ b)
{
  int row = blockIdx.x;
  const bf16* orow; bf16* hrow; float sk;
  if (row < NP) {
    orow = oplP + (size_t)row * HID; hrow = hP + (size_t)row * HID; sk = skip2[0];
  } else {
    int r = row - NP;
    orow = oplA + (size_t)r * HID; hrow = hA + (size_t)r * HID; sk = skip2[1];
  }
  float sp = 1.f / (1.f + expf(-sk));
  int t = threadIdx.x;
  ushort2 ov = ((const ushort2*)orow)[t];
  ushort2 hv = ((ushort2*)hrow)[t];
  float t0 = sp * bu2f(ov.x) + (2.f - sp) * bu2f(hv.x);
  float t1 = sp * bu2f(ov.y) + (2.f - sp) * bu2f(hv.y);
  float s = t0 + t1, ss = t0 * t0 + t1 * t1;
#pragma unroll
  for (int off = 32; off; off >>= 1) {
    s += __shfl_down(s, off);
    ss += __shfl_down(ss, off);
  }
  __shared__ float sh[8];
  int wid = t >> 6, lane = t & 63;
  if (lane == 0) { sh[wid] = s; sh[4 + wid] = ss; }
  __syncthreads();
  if (t == 0) {
    float S = 0, SS = 0;
    for (int wv = 0; wv < 4; wv++) { S += sh[wv]; SS += sh[4 + wv]; }
    sh[0] = S; sh[4] = SS;
  }
  __syncthreads();
  float mu = sh[0] * (1.f / 512.f);
  float var = sh[4] * (1.f / 512.f) - mu * mu;
  float inv = rsqrtf(var + 1e-5f);
  float y0 = (t0 - mu) * inv * g[2 * t] + b[2 * t];
  float y1 = (t1 - mu) * inv * g[2 * t + 1] + b[2 * t + 1];
  ushort2 o;
  o.x = f2bu(fmaxf(y0, 0.f));
  o.y = f2bu(fmaxf(y1, 0.f));
  ((ushort2*)hrow)[t] = o;
}

// ---------------------------------------------------------------------------
static inline void mgemm2(GemmPair gp, int N0, int N1, hipStream_t s)
{
  gp.nbn0 = N0 / 128;
  gp.nbn1 = N1 / 128;
  int nw0 = ((gp.M0 + 127) / 128) * gp.nbn0;
  int nw1 = ((gp.M1 + 127) / 128) * gp.nbn1;
  gp.nw0 = nw0;
  mfma_gemm2<<<dim3(nw0 + nw1), 256, 0, s>>>(gp);
}

extern "C" void kernel_launch(void* const* d_in, const int* in_sizes, int n_in,
                              void* d_out, int out_size, void* d_ws, size_t ws_size,
                              hipStream_t stream)
{
  const float* x_paper  = (const float*)d_in[0];
  const float* x_author = (const float*)d_in[1];
  const float* Wp_paper = (const float*)d_in[2];
  const float* bp_paper = (const float*)d_in[3];
  const float* Wp_author= (const float*)d_in[4];
  const float* bp_author= (const float*)d_in[5];
  const float* Wk = (const float*)d_in[6];
  const float* bk = (const float*)d_in[7];
  const float* Wq = (const float*)d_in[8];
  const float* bq = (const float*)d_in[9];
  const float* Wv = (const float*)d_in[10];
  const float* bv = (const float*)d_in[11];
  const float* Wa = (const float*)d_in[12];
  const float* ba = (const float*)d_in[13];
  const float* skip = (const float*)d_in[14];
  const float* a_rel = (const float*)d_in[15];
  const float* m_rel = (const float*)d_in[16];
  const float* p_rel = (const float*)d_in[17];
  const float* ln_g = (const float*)d_in[18];
  const float* ln_b = (const float*)d_in[19];
  const float* W256 = (const float*)d_in[20];
  const float* b256 = (const float*)d_in[21];
  const float* W128 = (const float*)d_in[22];
  const float* b128 = (const float*)d_in[23];
  const int* ei_c = (const int*)d_in[24];
  const int* ei_w = (const int*)d_in[25];
  const int* ei_b = (const int*)d_in[26];
  float* out = (float*)d_out;

  const size_t NPe = (size_t)NP * HID, NAe = (size_t)NA * HID;
  const size_t HH = (size_t)HID * HID;
  char* w = (char*)d_ws;
  size_t off = 0;
  auto alloc = [&](size_t bytes) -> void* {
    void* p = (void*)(w + off);
    off += (bytes + 255) & ~(size_t)255;
    return p;
  };
  bf16* hb_p  = (bf16*)alloc(NPe * 2);
  bf16* hb_a  = (bf16*)alloc(NAe * 2);
  bf16* qkv_p = (bf16*)alloc((size_t)NP * NQP * 2);
  bf16* qkv_a = (bf16*)alloc((size_t)NA * NQA * 2);
  bf16* ag_p  = (bf16*)alloc(NPe * 2);
  bf16* ag_a  = (bf16*)alloc(NAe * 2);
  float* Wf32 = (float*)alloc(12 * HH * 4);
  bf16* WBtP  = (bf16*)alloc((size_t)2 * NQP * HID * 2);
  bf16* WBtA  = (bf16*)alloc((size_t)2 * NQA * HID * 2);
  float* pbP  = (float*)alloc((size_t)2 * NQP * 4);
  float* pbA  = (float*)alloc((size_t)2 * NQA * 4);
  bf16* WaT   = (bf16*)alloc(4 * HH * 2);
  bf16* W256T = (bf16*)alloc((size_t)HID * 256 * 2);
  bf16* W128T = (bf16*)alloc((size_t)256 * 128 * 2);
  bf16* WpTp  = (bf16*)alloc((size_t)INDIM * HID * 2);
  bf16* WpTa  = (bf16*)alloc((size_t)INDIM * HID * 2);
  int* rowptrP = (int*)alloc((size_t)(NP + 1) * 4);
  int* rowptrA = (int*)alloc((size_t)(NA + 1) * 4);
  int* degP    = (int*)alloc((size_t)(2 * NP + 2 * NA) * 4);  // degP|degA|curP|curA
  int* degA    = degP + NP;
  int* curP    = degA + NA;
  int* curA    = curP + NP;
  int* srcsP   = (int*)alloc((size_t)(EC + EW) * 4);
  int* srcsA   = (int*)alloc((size_t)EB * 4);
  int* bsumP   = (int*)alloc(64 * 4);
  int* bsumA   = (int*)alloc(64 * 4);
  if (off > ws_size) return;

  const float scale = 0.08838834764831845f;  // 1/sqrt(128)

  // --- CSR build (merged launches) ---
  (void)hipMemsetAsync(degP, 0, (size_t)(2 * NP + 2 * NA) * 4, stream);
  build_hist3<<<dim3((EC + EW + EB + 255) / 256), 256, 0, stream>>>(ei_c, ei_w, ei_b, degP, degA);
  scan_blk2<<<dim3(NBP + NBA), 256, 0, stream>>>(degP, rowptrP, bsumP, degA, rowptrA, bsumA);
  scan_bsum2<<<dim3(2), 64, 0, stream>>>(bsumP, rowptrP + NP, bsumA, rowptrA + NA);
  scan_add2<<<dim3(NBP + NBA), 256, 0, stream>>>(rowptrP, bsumP, rowptrA, bsumA);
  build_scatter3<<<dim3((EC + EW + EB + 255) / 256), 256, 0, stream>>>(
      ei_c, ei_w, ei_b, rowptrP, curP, srcsP, rowptrA, curA, srcsA);

  // --- fused relation weights + layer packs ---
  FuseArgs fa;
  TrArgs ta;
  CopyB cb;
  for (int l = 0; l < NLAY; l++) {
    bf16* packP = WBtP + (size_t)l * NQP * HID;
    bf16* packA = WBtA + (size_t)l * NQA * HID;
    float* pbPl = pbP + (size_t)l * NQP;
    float* pbAl = pbA + (size_t)l * NQA;
    for (int r = 0; r < 3; r++)
      for (int s = 0; s < 2; s++) {
        int c = (l * 3 + r) * 2 + s;
        int t = (r == 1) ? 1 : 0;
        fa.W[c]   = (s == 0 ? Wk : Wv) + (size_t)(l * 2 + t) * HH;
        fa.rel[c] = (s == 0 ? a_rel : m_rel) + (size_t)(l * 3 + r) * NHEAD * DH * DH;
        fa.bin[c] = (s == 0 ? bk : bv) + (size_t)(l * 2 + t) * HID;
        fa.out[c] = Wf32 + (size_t)c * HH;
        ta.src[c] = fa.out[c];
        if (r == 0) {
          ta.dst[c]  = packP + (size_t)(512 + s * 512) * HID;
          fa.bout[c] = pbPl + 512 + s * 512;
        } else if (r == 1) {
          ta.dst[c]  = packA + (size_t)(512 + s * 512) * HID;
          fa.bout[c] = pbAl + 512 + s * 512;
        } else {
          ta.dst[c]  = packP + (size_t)(1536 + s * 512) * HID;
          fa.bout[c] = pbPl + 1536 + s * 512;
        }
      }
    ta.src[12 + l * 2 + 0] = Wq + (size_t)(l * 2 + 0) * HH;
    ta.dst[12 + l * 2 + 0] = packP;
    ta.src[12 + l * 2 + 1] = Wq + (size_t)(l * 2 + 1) * HH;
    ta.dst[12 + l * 2 + 1] = packA;
    ta.src[16 + l * 2 + 0] = Wa + (size_t)(l * 2 + 0) * HH;
    ta.dst[16 + l * 2 + 0] = WaT + (size_t)(l * 2 + 0) * HH;
    ta.src[16 + l * 2 + 1] = Wa + (size_t)(l * 2 + 1) * HH;
    ta.dst[16 + l * 2 + 1] = WaT + (size_t)(l * 2 + 1) * HH;
    cb.src[l * 2 + 0] = bq + (size_t)(l * 2 + 0) * HID;
    cb.dst[l * 2 + 0] = pbPl;
    cb.src[l * 2 + 1] = bq + (size_t)(l * 2 + 1) * HID;
    cb.dst[l * 2 + 1] = pbAl;
  }
  gemm_fuse<<<dim3(8, 2, 48), 256, 0, stream>>>(fa);
  transpose20<<<dim3(16, 16, 20), dim3(32, 8), 0, stream>>>(ta);
  bias_fuse_all<<<dim3(12), 512, 0, stream>>>(fa);
  copy_bias<<<dim3(4), 512, 0, stream>>>(cb);
  {
    dim3 b(32, 8);
    transpose_to_bf16<<<dim3(8, 16), b, 0, stream>>>(W256, W256T, HID, 256);
    transpose_to_bf16<<<dim3(4, 8), b, 0, stream>>>(W128, W128T, 256, 128);
    transpose_to_bf16<<<dim3(16, 24), b, 0, stream>>>(Wp_paper, WpTp, INDIM, HID);
    transpose_to_bf16<<<dim3(16, 24), b, 0, stream>>>(Wp_author, WpTa, INDIM, HID);
  }

  // --- input conversion + projection ---
  bf16* xb_p = qkv_p;
  bf16* xb_a = qkv_a;
  long long nxp = (long long)NP * INDIM, nxa = (long long)NA * INDIM;
  f32_to_bf16_2<<<dim3((int)(((nxp + nxa) / 4 + 255) / 256)), 256, 0, stream>>>(
      x_paper, xb_p, nxp, x_author, xb_a, nxa);
  {
    GemmPair gp{};
    gp.A0 = xb_p; gp.lda0 = INDIM; gp.B0 = WpTp; gp.ldb0 = INDIM;
    gp.b0 = bp_paper; gp.C0 = hb_p; gp.ldc0 = HID;
    gp.M0 = NP; gp.K0 = INDIM; gp.act0 = 0; gp.bf0 = 1;
    gp.A1 = xb_a; gp.lda1 = INDIM; gp.B1 = WpTa; gp.ldb1 = INDIM;
    gp.b1 = bp_author; gp.C1 = hb_a; gp.ldc1 = HID;
    gp.M1 = NA; gp.K1 = INDIM; gp.act1 = 0; gp.bf1 = 1;
    mgemm2(gp, HID, HID, stream);
  }

  for (int l = 0; l < NLAY; l++) {
    const float* prl = p_rel + (size_t)l * 3 * NHEAD;
    const bf16* packP = WBtP + (size_t)l * NQP * HID;
    const bf16* packA = WBtA + (size_t)l * NQA * HID;
    const float* pbPl = pbP + (size_t)l * NQP;
    const float* pbAl = pbA + (size_t)l * NQA;

    // fused projections pair: q|kv0|kv2 (paper) + q|kv1 (author)
    {
      GemmPair gp{};
      gp.A0 = hb_p; gp.lda0 = HID; gp.B0 = packP; gp.ldb0 = HID;
      gp.b0 = pbPl; gp.C0 = qkv_p; gp.ldc0 = NQP;
      gp.M0 = NP; gp.K0 = HID; gp.act0 = 0; gp.bf0 = 1;
      gp.A1 = hb_a; gp.lda1 = HID; gp.B1 = packA; gp.ldb1 = HID;
      gp.b1 = pbAl; gp.C1 = qkv_a; gp.ldc1 = NQA;
      gp.M1 = NA; gp.K1 = HID; gp.act1 = 0; gp.bf1 = 1;
      mgemm2(gp, NQP, NQA, stream);
    }
    // merged one-pass attention + gelu
    csr_attn_agg2<<<dim3((NP + NA + 3) / 4), 256, 0, stream>>>(
        rowptrP, srcsP, rowptrA, srcsA, qkv_p, qkv_a, prl, scale, ag_p, ag_a);
    // output linear pair (bf16 out into dead qkv slabs)
    bf16* opl_p = qkv_p;
    bf16* opl_a = qkv_a;
    {
      GemmPair gp{};
      gp.A0 = ag_p; gp.lda0 = HID; gp.B0 = WaT + (size_t)(l * 2 + 0) * HH; gp.ldb0 = HID;
      gp.b0 = ba + (size_t)(l * 2 + 0) * HID; gp.C0 = opl_p; gp.ldc0 = HID;
      gp.M0 = NP; gp.K0 = HID; gp.act0 = 0; gp.bf0 = 1;
      gp.A1 = ag_a; gp.lda1 = HID; gp.B1 = WaT + (size_t)(l * 2 + 1) * HH; gp.ldb1 = HID;
      gp.b1 = ba + (size_t)(l * 2 + 1) * HID; gp.C1 = opl_a; gp.ldc1 = HID;
      gp.M1 = NA; gp.K1 = HID; gp.act1 = 0; gp.bf1 = 1;
      mgemm2(gp, HID, HID, stream);
    }
    // merged skip + residual + LN + relu
    skip_ln_relu2<<<dim3(NP + NA), 256, 0, stream>>>(
        opl_p, opl_a, hb_p, hb_a, skip + l * 2,
        ln_g + (size_t)l * HID, ln_b + (size_t)l * HID);
  }

  // final MLP
  bf16* h256_p = ag_p;
  bf16* h256_a = ag_a;
  {
    GemmPair gp{};
    gp.A0 = hb_p; gp.lda0 = HID; gp.B0 = W256T; gp.ldb0 = HID;
    gp.b0 = b256; gp.C0 = h256_p; gp.ldc0 = 256;
    gp.M0 = NP; gp.K0 = HID; gp.act0 = 1; gp.bf0 = 1;
    gp.A1 = hb_a; gp.lda1 = HID; gp.B1 = W256T; gp.ldb1 = HID;
    gp.b1 = b256; gp.C1 = h256_a; gp.ldc1 = 256;
    gp.M1 = NA; gp.K1 = HID; gp.act1 = 1; gp.bf1 = 1;
    mgemm2(gp, 256, 256, stream);
  }
  {
    GemmPair gp{};
    gp.A0 = h256_p; gp.lda0 = 256; gp.B0 = W128T; gp.ldb0 = 256;
    gp.b0 = b128; gp.C0 = out; gp.ldc0 = 128;
    gp.M0 = NP; gp.K0 = 256; gp.act0 = 0; gp.bf0 = 0;
    gp.A1 = h256_a; gp.lda1 = 256; gp.B1 = W128T; gp.ldb1 = 256;
    gp.b1 = b128; gp.C1 = out + (size_t)NP * 128; gp.ldc1 = 128;
    gp.M1 = NA; gp.K1 = 256; gp.act1 = 0; gp.bf1 = 0;
    mgemm2(gp, 128, 128, stream);
  }
}

// Round 18
// 816.225 us; speedup vs baseline: 1.0928x; 1.0008x over previous
//
#include <hip/hip_runtime.h>
#include <hip/hip_bf16.h>
#include <math.h>

#define NHEAD 4
#define DH 128
#define HID 512
#define NLAY 2
#define NP 30000
#define NA 10000
#define INDIM 768
#define EC 150000
#define EW 80000
#define EB 80000
#define NQP 2560   // q | kv0 | kv2
#define NQA 1536   // q | kv1

typedef __hip_bfloat16 bf16;
typedef __attribute__((ext_vector_type(8))) short bf16x8;
typedef __attribute__((ext_vector_type(4))) float f32x4;
typedef __attribute__((ext_vector_type(4))) unsigned int u32x4;

__device__ __forceinline__ unsigned short f2bu(float f){ bf16 t = __float2bfloat16(f); return *(unsigned short*)&t; }
__device__ __forceinline__ float bu2f(unsigned short u){ return __uint_as_float((unsigned)u << 16); }

__device__ __forceinline__ void load8b(const bf16* __restrict__ p, int i8, float* o){
  uint4 r = ((const uint4*)p)[i8];
  o[0]=__uint_as_float(r.x<<16); o[1]=__uint_as_float(r.x&0xffff0000u);
  o[2]=__uint_as_float(r.y<<16); o[3]=__uint_as_float(r.y&0xffff0000u);
  o[4]=__uint_as_float(r.z<<16); o[5]=__uint_as_float(r.z&0xffff0000u);
  o[6]=__uint_as_float(r.w<<16); o[7]=__uint_as_float(r.w&0xffff0000u);
}

// async global->LDS, 16B per lane, wave-uniform LDS base + lane*16
__device__ __forceinline__ void gload16(const void* g, void* l) {
  __builtin_amdgcn_global_load_lds((const __attribute__((address_space(1))) void*)g,
                                   (__attribute__((address_space(3))) void*)l, 16, 0, 0);
}

// ---------------------------------------------------------------------------
// Paired MFMA bf16 GEMM (r12 structure + r17 occupancy cap): two sub-GEMMs
// in ONE launch. 128x128 tile, BK=64, single-buffered 33.8KB LDS.
// __launch_bounds__(256,4): caps total regs/wave at 128 (64 acc + ~60 arch)
// -> 4 waves/SIMD (verified r17: VGPR 80->60, Occ 31->40, pair 167->145us).
// bf16 C: full-tile LDS-bounce epilogue -> 16B/lane NT stores. fp32 C: NT.
// ---------------------------------------------------------------------------
struct GemmPair {
  const bf16 *A0, *A1, *B0, *B1;
  const float *b0, *b1;
  void *C0, *C1;
  int lda0, lda1, ldb0, ldb1, ldc0, ldc1;
  int M0, M1, K0, K1;
  int act0, act1, bf0, bf1;      // bfX: 1 = bf16 C, 0 = fp32 C
  int nbn0, nbn1, nw0;
};

#define TSTRIDE 132   // padded bf16 epilogue stride

__global__ __launch_bounds__(256, 4)
void mfma_gemm2(GemmPair gp)
{
  __shared__ __align__(16) short smem[128 * TSTRIDE];  // 33.8 KB
  const int tid = threadIdx.x;
  const int lane = tid & 63, w = tid >> 6;
  const int nwg = gridDim.x;
  const int bid = blockIdx.x;
  const int xcd = bid & 7, pos = bid >> 3;
  const int q8 = nwg >> 3, r8 = nwg & 7;
  const int work = (xcd < r8 ? xcd * (q8 + 1) : r8 * (q8 + 1) + (xcd - r8) * q8) + pos;
  const int g = work >= gp.nw0;
  const int w2 = g ? work - gp.nw0 : work;
  const bf16* A  = g ? gp.A1 : gp.A0;
  const bf16* Bt = g ? gp.B1 : gp.B0;
  const float* bias = g ? gp.b1 : gp.b0;
  void* Cv = g ? gp.C1 : gp.C0;
  const int lda = g ? gp.lda1 : gp.lda0;
  const int ldb = g ? gp.ldb1 : gp.ldb0;
  const int ldc = g ? gp.ldc1 : gp.ldc0;
  const int M = g ? gp.M1 : gp.M0;
  const int K = g ? gp.K1 : gp.K0;
  const int act = g ? gp.act1 : gp.act0;
  const int isbf = g ? gp.bf1 : gp.bf0;
  const int nbn = g ? gp.nbn1 : gp.nbn0;
  const int brow = (w2 / nbn) * 128, bcol = (w2 % nbn) * 128;
  const int wr = w >> 1, wc = w & 1;

  f32x4 acc[4][4];
#pragma unroll
  for (int m = 0; m < 4; m++)
#pragma unroll
    for (int n = 0; n < 4; n++) acc[m][n] = (f32x4){0.f, 0.f, 0.f, 0.f};

  short* Asb = smem;
  short* Bsb = smem + 8192;
  const int nk = K >> 6;
  for (int t = 0; t < nk; t++) {
    const int k0 = t << 6;
#pragma unroll
    for (int i = 0; i < 4; i++) {
      int chunk = i * 4 + w;                   // wave-uniform
      int c_lin = chunk * 64 + lane;
      int row = c_lin >> 3;
      int kc = ((c_lin & 7) ^ (row & 7)) * 8;  // inverse-swizzled source k
      int growA = brow + row; growA = growA < M ? growA : M - 1;
      gload16(A + (size_t)growA * lda + k0 + kc, Asb + chunk * 512);
      gload16(Bt + (size_t)(bcol + row) * ldb + k0 + kc, Bsb + chunk * 512);
    }
    __syncthreads();   // drains vmcnt: staged tile visible
#pragma unroll
    for (int kk = 0; kk < 2; kk++) {
      const int ke = kk * 32 + (lane >> 4) * 8;
      bf16x8 af[4], bq[4];
#pragma unroll
      for (int m = 0; m < 4; m++) {
        int row = wr * 64 + m * 16 + (lane & 15);
        af[m] = *(const bf16x8*)(Asb + row * 64 + (ke ^ ((row & 7) << 3)));
      }
#pragma unroll
      for (int n = 0; n < 4; n++) {
        int col = wc * 64 + n * 16 + (lane & 15);
        bq[n] = *(const bf16x8*)(Bsb + col * 64 + (ke ^ ((col & 7) << 3)));
      }
#pragma unroll
      for (int m = 0; m < 4; m++)
#pragma unroll
        for (int n = 0; n < 4; n++)
          acc[m][n] = __builtin_amdgcn_mfma_f32_16x16x32_bf16(af[m], bq[n], acc[m][n], 0, 0, 0);
    }
    __syncthreads();   // all waves done reading before next stage overwrites
  }

  if (isbf) {
    // ---- LDS-bounce epilogue ----
#pragma unroll
    for (int m = 0; m < 4; m++) {
      int row0 = wr * 64 + m * 16 + (lane >> 4) * 4;
#pragma unroll
      for (int n = 0; n < 4; n++) {
        int col = wc * 64 + n * 16 + (lane & 15);
        float bv = bias ? bias[bcol + col] : 0.f;
#pragma unroll
        for (int r = 0; r < 4; r++) {
          float v = acc[m][n][r] + bv;
          if (act) v = fmaxf(v, 0.f);
          smem[(row0 + r) * TSTRIDE + col] = (short)f2bu(v);
        }
      }
    }
    __syncthreads();
#pragma unroll
    for (int it = 0; it < 8; it++) {
      int chunk = it * 256 + tid;        // 0..2047 : 128 rows x 16 chunks of 16B
      int row = chunk >> 4, c16 = chunk & 15;
      int gr = brow + row;
      if (gr < M) {
        u32x4 v = *(const u32x4*)(smem + row * TSTRIDE + c16 * 8);
        __builtin_nontemporal_store(v,
            (u32x4*)((unsigned short*)Cv + (size_t)gr * ldc + bcol + c16 * 8));
      }
    }
  } else {
    // fp32 C: direct NT (16 lanes x 4B = full 64B line)
#pragma unroll
    for (int m = 0; m < 4; m++) {
      int gr0 = brow + wr * 64 + m * 16 + (lane >> 4) * 4;
#pragma unroll
      for (int n = 0; n < 4; n++) {
        int gc = bcol + wc * 64 + n * 16 + (lane & 15);
        float bv = bias ? bias[gc] : 0.f;
#pragma unroll
        for (int r = 0; r < 4; r++) {
          int gr = gr0 + r;
          if (gr < M) {
            float v = acc[m][n][r] + bv;
            if (act) v = fmaxf(v, 0.f);
            __builtin_nontemporal_store(v, (float*)Cv + (size_t)gr * ldc + gc);
          }
        }
      }
    }
  }
}

// ---------------------------------------------------------------------------
// Weight preparation
// ---------------------------------------------------------------------------
struct FuseArgs {
  const float* W[12];
  const float* rel[12];
  const float* bin[12];
  float* out[12];
  float* bout[12];
};
struct TrArgs {
  const float* src[20];
  bf16* dst[20];
};
struct CopyB { const float* src[4]; float* dst[4]; };

__global__ __launch_bounds__(256)
void gemm_fuse(FuseArgs fa)
{
  int c = blockIdx.z >> 2, h = blockIdx.z & 3;
  const float* A = fa.W[c] + h * 128;
  const float* B = fa.rel[c] + (size_t)h * 128 * 128;
  float* C = fa.out[c] + h * 128;
  __shared__ float Ast[64][17];
  __shared__ float Bst[16][64];
  const int tid = threadIdx.x;
  const int tx = tid & 15, ty = tid >> 4;
  const int bm = blockIdx.x * 64, bn = blockIdx.y * 64;
  float acc[4][4] = {};
  for (int k0 = 0; k0 < 128; k0 += 16) {
#pragma unroll
    for (int i = 0; i < 4; i++) {
      int lin = tid + i * 256;
      int m = lin >> 4, kk = lin & 15;
      Ast[m][kk] = A[(size_t)(bm + m) * 512 + k0 + kk];
      int kb = lin >> 6, nb = lin & 63;
      Bst[kb][nb] = B[(size_t)(k0 + kb) * 128 + bn + nb];
    }
    __syncthreads();
#pragma unroll
    for (int kk = 0; kk < 16; kk++) {
      float a[4], b[4];
#pragma unroll
      for (int i = 0; i < 4; i++) a[i] = Ast[ty * 4 + i][kk];
#pragma unroll
      for (int j = 0; j < 4; j++) b[j] = Bst[kk][tx * 4 + j];
#pragma unroll
      for (int i = 0; i < 4; i++)
#pragma unroll
        for (int j = 0; j < 4; j++)
          acc[i][j] = fmaf(a[i], b[j], acc[i][j]);
    }
    __syncthreads();
  }
#pragma unroll
  for (int i = 0; i < 4; i++)
#pragma unroll
    for (int j = 0; j < 4; j++)
      C[(size_t)(bm + ty * 4 + i) * 512 + bn + tx * 4 + j] = acc[i][j];
}

__global__ __launch_bounds__(256)
void transpose20(TrArgs ta)
{
  int c = blockIdx.z;
  const float* in = ta.src[c];
  bf16* o = ta.dst[c];
  __shared__ float t[32][33];
  int bn = blockIdx.x * 32, bk = blockIdx.y * 32;
  int x = threadIdx.x, y = threadIdx.y;
#pragma unroll
  for (int i = 0; i < 32; i += 8)
    t[y + i][x] = in[(size_t)(bk + y + i) * 512 + bn + x];
  __syncthreads();
#pragma unroll
  for (int i = 0; i < 32; i += 8)
    o[(size_t)(bn + y + i) * 512 + bk + x] = __float2bfloat16(t[x][y + i]);
}

__global__ __launch_bounds__(512)
void bias_fuse_all(FuseArgs fa)
{
  int c = blockIdx.x;
  int j = threadIdx.x;
  int h = j >> 7, e = j & 127;
  const float* bh = fa.bin[c] + h * DH;
  const float* rh = fa.rel[c] + (size_t)h * DH * DH;
  float s = 0.f;
  for (int d = 0; d < DH; d++) s = fmaf(bh[d], rh[d * DH + e], s);
  fa.bout[c][j] = s;
}

__global__ __launch_bounds__(512)
void copy_bias(CopyB cb)
{
  cb.dst[blockIdx.x][threadIdx.x] = cb.src[blockIdx.x][threadIdx.x];
}

__global__ __launch_bounds__(256)
void transpose_to_bf16(const float* __restrict__ in, bf16* __restrict__ out,
                       int K_, int N_)
{
  __shared__ float t[32][33];
  int bn = blockIdx.x * 32, bk = blockIdx.y * 32;
  int x = threadIdx.x, y = threadIdx.y;
#pragma unroll
  for (int i = 0; i < 32; i += 8) {
    int k = bk + y + i, n = bn + x;
    if (k < K_ && n < N_) t[y + i][x] = in[(size_t)k * N_ + n];
  }
  __syncthreads();
#pragma unroll
  for (int i = 0; i < 32; i += 8) {
    int n = bn + y + i, k = bk + x;
    if (n < N_ && k < K_) out[(size_t)n * K_ + k] = __float2bfloat16(t[x][y + i]);
  }
}

__global__ __launch_bounds__(256)
void f32_to_bf16_2(const float* __restrict__ s0, bf16* __restrict__ d0, long long n0,
                   const float* __restrict__ s1, bf16* __restrict__ d1, long long n1)
{
  long long i = ((long long)blockIdx.x * 256 + threadIdx.x) * 4;
  const float* s; bf16* d;
  if (i < n0) { s = s0; d = d0; }
  else { i -= n0; if (i >= n1) return; s = s1; d = d1; }
  float4 v = *(const float4*)(s + i);
  ushort4 o;
  o.x = f2bu(v.x); o.y = f2bu(v.y); o.z = f2bu(v.z); o.w = f2bu(v.w);
  *(ushort4*)(d + i) = o;
}

// ---------------------------------------------------------------------------
// CSR build (merged launches)
// ---------------------------------------------------------------------------
__global__ __launch_bounds__(256)
void build_hist3(const int* __restrict__ eiC, const int* __restrict__ eiW,
                 const int* __restrict__ eiB,
                 int* __restrict__ degP, int* __restrict__ degA)
{
  int i = blockIdx.x * 256 + threadIdx.x;
  if (i < EC) atomicAdd(&degP[eiC[EC + i]], 1);
  else if (i < EC + EW) atomicAdd(&degP[eiW[EW + (i - EC)]], 1);
  else if (i < EC + EW + EB) atomicAdd(&degA[eiB[EB + (i - EC - EW)]], 1);
}

__device__ __forceinline__ void scan_blk_body(const int* __restrict__ deg, int n,
                                              int* __restrict__ rowptr,
                                              int* __restrict__ bsum, int blk)
{
  __shared__ int sh[256];
  int t = threadIdx.x;
  int base = blk * 1024 + t * 4;
  int v0 = 0, v1 = 0, v2 = 0, v3 = 0;
  if (base + 3 < n) {
    int4 v = *(const int4*)(deg + base);
    v0 = v.x; v1 = v.y; v2 = v.z; v3 = v.w;
  } else {
    if (base < n)     v0 = deg[base];
    if (base + 1 < n) v1 = deg[base + 1];
    if (base + 2 < n) v2 = deg[base + 2];
    if (base + 3 < n) v3 = deg[base + 3];
  }
  int s = v0 + v1 + v2 + v3;
  sh[t] = s;
  __syncthreads();
#pragma unroll
  for (int off = 1; off < 256; off <<= 1) {
    int tv = (t >= off) ? sh[t - off] : 0;
    __syncthreads();
    sh[t] += tv;
    __syncthreads();
  }
  int excl = sh[t] - s;
  if (t == 255) bsum[blk] = sh[255];
  if (base < n)     rowptr[base] = excl;
  if (base + 1 < n) rowptr[base + 1] = excl + v0;
  if (base + 2 < n) rowptr[base + 2] = excl + v0 + v1;
  if (base + 3 < n) rowptr[base + 3] = excl + v0 + v1 + v2;
}

#define NBP ((NP + 1023) / 1024)
#define NBA ((NA + 1023) / 1024)

__global__ __launch_bounds__(256)
void scan_blk2(const int* __restrict__ degP, int* __restrict__ rowptrP, int* __restrict__ bsumP,
               const int* __restrict__ degA, int* __restrict__ rowptrA, int* __restrict__ bsumA)
{
  if (blockIdx.x < NBP) scan_blk_body(degP, NP, rowptrP, bsumP, blockIdx.x);
  else                  scan_blk_body(degA, NA, rowptrA, bsumA, blockIdx.x - NBP);
}

__global__ __launch_bounds__(64)
void scan_bsum2(int* __restrict__ bsumP, int* __restrict__ endP,
                int* __restrict__ bsumA, int* __restrict__ endA)
{
  int* bsum = blockIdx.x ? bsumA : bsumP;
  int nb = blockIdx.x ? NBA : NBP;
  int* rpe = blockIdx.x ? endA : endP;
  int t = threadIdx.x;
  int v = (t < nb) ? bsum[t] : 0;
  int inc = v;
#pragma unroll
  for (int off = 1; off < 64; off <<= 1) {
    int o = __shfl_up(inc, off);
    if (t >= off) inc += o;
  }
  if (t < nb) bsum[t] = inc - v;
  if (t == nb - 1) *rpe = inc;
}

__global__ __launch_bounds__(256)
void scan_add2(int* __restrict__ rowptrP, const int* __restrict__ bsumP,
               int* __restrict__ rowptrA, const int* __restrict__ bsumA)
{
  int* rowptr; const int* bsum; int n, blk;
  if (blockIdx.x < NBP) { rowptr = rowptrP; bsum = bsumP; n = NP; blk = blockIdx.x; }
  else                  { rowptr = rowptrA; bsum = bsumA; n = NA; blk = blockIdx.x - NBP; }
  int add = bsum[blk];
  if (add == 0) return;
  int i = blk * 1024 + threadIdx.x * 4;
  if (i < n)     rowptr[i] += add;
  if (i + 1 < n) rowptr[i + 1] += add;
  if (i + 2 < n) rowptr[i + 2] += add;
  if (i + 3 < n) rowptr[i + 3] += add;
}

__global__ __launch_bounds__(256)
void build_scatter3(const int* __restrict__ eiC, const int* __restrict__ eiW,
                    const int* __restrict__ eiB,
                    const int* __restrict__ rowptrP, int* __restrict__ curP,
                    int* __restrict__ srcsP,
                    const int* __restrict__ rowptrA, int* __restrict__ curA,
                    int* __restrict__ srcsA)
{
  int i = blockIdx.x * 256 + threadIdx.x;
  if (i < EC) {
    int src = eiC[i], dst = eiC[EC + i];
    int pos = rowptrP[dst] + atomicAdd(&curP[dst], 1);
    srcsP[pos] = src;
  } else if (i < EC + EW) {
    int e = i - EC;
    int src = eiW[e], dst = eiW[EW + e];
    int pos = rowptrP[dst] + atomicAdd(&curP[dst], 1);
    srcsP[pos] = src | 0x40000000;
  } else if (i < EC + EW + EB) {
    int e = i - EC - EW;
    int src = eiB[e], dst = eiB[EB + e];
    int pos = rowptrA[dst] + atomicAdd(&curA[dst], 1);
    srcsA[pos] = src;
  }
}

// ---------------------------------------------------------------------------
// Merged fused one-pass attention (paper + author). Online softmax w/
// defer-max THR=8 + exact gelu -> bf16. One 64-lane wave per node.
// Edge loop 2-stage software-pipelined. __launch_bounds__(256,6): cap regs
// at ~85/wave -> 6 waves/SIMD for more outstanding-gather parallelism
// (kernel is LLC-gather-latency-bound; same lever as r17's GEMM win).
// ---------------------------------------------------------------------------
__global__ __launch_bounds__(256, 6)
void csr_attn_agg2(const int* __restrict__ rowptrP, const int* __restrict__ srcsP,
                   const int* __restrict__ rowptrA, const int* __restrict__ srcsA,
                   const bf16* __restrict__ qkvP, const bf16* __restrict__ qkvA,
                   const float* __restrict__ prl, float scale,
                   bf16* __restrict__ agP, bf16* __restrict__ agA)
{
  int node = blockIdx.x * 4 + (threadIdx.x >> 6);
  int lane = threadIdx.x & 63;
  int h = lane >> 4;
  const int* rp; const int* srcs;
  const bf16* q; const bf16 *t0, *t1;
  int ld0, off0, ld1, off1;
  float p0, p1;
  bf16* outp;
  if (node < NP) {
    rp = rowptrP; srcs = srcsP;
    q = qkvP + (size_t)node * NQP;
    t0 = qkvP; ld0 = NQP; off0 = 512;
    t1 = qkvA; ld1 = NQA; off1 = 512;
    p0 = prl[h] * scale; p1 = prl[4 + h] * scale;
    outp = agP + (size_t)node * HID;
  } else {
    int r = node - NP;
    if (r >= NA) return;
    rp = rowptrA; srcs = srcsA; node = r;
    q = qkvA + (size_t)r * NQA;
    t0 = qkvP; ld0 = NQP; off0 = 1536;
    t1 = qkvP; ld1 = NQP; off1 = 1536;
    p0 = prl[8 + h] * scale; p1 = p0;
    outp = agA + (size_t)r * HID;
  }
  float qv[8];
  load8b(q, lane, qv);
  int beg = rp[node], end = rp[node + 1];
  float m = -INFINITY, s = 0.f;
  float acc[8] = {};
  float kv[8], vv[8];
  int se = 0;
  if (beg < end) {
    se = srcs[beg];
    int src = se & 0x3FFFFFFF;
    const bf16* row = (se & 0x40000000) ? (t1 + (size_t)src * ld1 + off1)
                                        : (t0 + (size_t)src * ld0 + off0);
    load8b(row, lane, kv);
    load8b(row + 512, lane, vv);
  }
  for (int p = beg; p < end; ++p) {
    bool f1 = (se & 0x40000000) != 0;
    float ckv[8], cvv[8];
#pragma unroll
    for (int i = 0; i < 8; i++) { ckv[i] = kv[i]; cvv[i] = vv[i]; }
    if (p + 1 < end) {
      se = srcs[p + 1];
      int src = se & 0x3FFFFFFF;
      const bf16* row = (se & 0x40000000) ? (t1 + (size_t)src * ld1 + off1)
                                          : (t0 + (size_t)src * ld0 + off0);
      load8b(row, lane, kv);        // issue next-edge loads before compute
      load8b(row + 512, lane, vv);
    }
    float a = 0.f;
#pragma unroll
    for (int i = 0; i < 8; i++) a = fmaf(qv[i], ckv[i], a);
    a += __shfl_xor(a, 1);
    a += __shfl_xor(a, 2);
    a += __shfl_xor(a, 4);
    a += __shfl_xor(a, 8);
    a *= f1 ? p1 : p0;
    if (a > m + 8.f) {              // defer-max (T13)
      float sc = __expf(m - a);
      s *= sc;
#pragma unroll
      for (int i = 0; i < 8; i++) acc[i] *= sc;
      m = a;
    }
    float wgt = __expf(a - m);
    s += wgt;
#pragma unroll
    for (int i = 0; i < 8; i++) acc[i] = fmaf(wgt, cvv[i], acc[i]);
  }
  float inv = 1.f / (s + 1e-16f);
  unsigned short gg[8];
#pragma unroll
  for (int i = 0; i < 8; i++) {
    float v = acc[i] * inv;
    gg[i] = f2bu(0.5f * v * (1.f + erff(v * 0.70710678118654752f)));
  }
  uint4 o;
  o.x = gg[0] | ((unsigned)gg[1] << 16);
  o.y = gg[2] | ((unsigned)gg[3] << 16);
  o.z = gg[4] | ((unsigned)gg[5] << 16);
  o.w = gg[6] | ((unsigned)gg[7] << 16);
  *(uint4*)(outp + lane * 8) = o;
}

// merged skip+residual+LN+relu (paper + author); oplin bf16, h bf16 in/out
__global__ __launch_bounds__(256)
void skip_ln_relu2(const bf16* __restrict__ oplP, const bf16* __restrict__ oplA,
                   bf16* __restrict__ hP, bf16* __restrict__ hA,
                   const float* __restrict__ skip2,
                   const float* __restrict__ g, const float* __restrict__ b)
{
  int row = blockIdx.x;
  const bf16* orow; bf16* hrow; float sk;
  if (row < NP) {
    orow = oplP + (size_t)row * HID; hrow = hP + (size_t)row * HID; sk = skip2[0];
  } else {
    int r = row - NP;
    orow = oplA + (size_t)r * HID; hrow = hA + (size_t)r * HID; sk = skip2[1];
  }
  float sp = 1.f / (1.f + expf(-sk));
  int t = threadIdx.x;
  ushort2 ov = ((const ushort2*)orow)[t];
  ushort2 hv = ((ushort2*)hrow)[t];
  float t0 = sp * bu2f(ov.x) + (2.f - sp) * bu2f(hv.x);
  float t1 = sp * bu2f(ov.y) + (2.f - sp) * bu2f(hv.y);
  float s = t0 + t1, ss = t0 * t0 + t1 * t1;
#pragma unroll
  for (int off = 32; off; off >>= 1) {
    s += __shfl_down(s, off);
    ss += __shfl_down(ss, off);
  }
  __shared__ float sh[8];
  int wid = t >> 6, lane = t & 63;
  if (lane == 0) { sh[wid] = s; sh[4 + wid] = ss; }
  __syncthreads();
  if (t == 0) {
    float S = 0, SS = 0;
    for (int wv = 0; wv < 4; wv++) { S += sh[wv]; SS += sh[4 + wv]; }
    sh[0] = S; sh[4] = SS;
  }
  __syncthreads();
  float mu = sh[0] * (1.f / 512.f);
  float var = sh[4] * (1.f / 512.f) - mu * mu;
  float inv = rsqrtf(var + 1e-5f);
  float y0 = (t0 - mu) * inv * g[2 * t] + b[2 * t];
  float y1 = (t1 - mu) * inv * g[2 * t + 1] + b[2 * t + 1];
  ushort2 o;
  o.x = f2bu(fmaxf(y0, 0.f));
  o.y = f2bu(fmaxf(y1, 0.f));
  ((ushort2*)hrow)[t] = o;
}

// ---------------------------------------------------------------------------
static inline void mgemm2(GemmPair gp, int N0, int N1, hipStream_t s)
{
  gp.nbn0 = N0 / 128;
  gp.nbn1 = N1 / 128;
  int nw0 = ((gp.M0 + 127) / 128) * gp.nbn0;
  int nw1 = ((gp.M1 + 127) / 128) * gp.nbn1;
  gp.nw0 = nw0;
  mfma_gemm2<<<dim3(nw0 + nw1), 256, 0, s>>>(gp);
}

extern "C" void kernel_launch(void* const* d_in, const int* in_sizes, int n_in,
                              void* d_out, int out_size, void* d_ws, size_t ws_size,
                              hipStream_t stream)
{
  const float* x_paper  = (const float*)d_in[0];
  const float* x_author = (const float*)d_in[1];
  const float* Wp_paper = (const float*)d_in[2];
  const float* bp_paper = (const float*)d_in[3];
  const float* Wp_author= (const float*)d_in[4];
  const float* bp_author= (const float*)d_in[5];
  const float* Wk = (const float*)d_in[6];
  const float* bk = (const float*)d_in[7];
  const float* Wq = (const float*)d_in[8];
  const float* bq = (const float*)d_in[9];
  const float* Wv = (const float*)d_in[10];
  const float* bv = (const float*)d_in[11];
  const float* Wa = (const float*)d_in[12];
  const float* ba = (const float*)d_in[13];
  const float* skip = (const float*)d_in[14];
  const float* a_rel = (const float*)d_in[15];
  const float* m_rel = (const float*)d_in[16];
  const float* p_rel = (const float*)d_in[17];
  const float* ln_g = (const float*)d_in[18];
  const float* ln_b = (const float*)d_in[19];
  const float* W256 = (const float*)d_in[20];
  const float* b256 = (const float*)d_in[21];
  const float* W128 = (const float*)d_in[22];
  const float* b128 = (const float*)d_in[23];
  const int* ei_c = (const int*)d_in[24];
  const int* ei_w = (const int*)d_in[25];
  const int* ei_b = (const int*)d_in[26];
  float* out = (float*)d_out;

  const size_t NPe = (size_t)NP * HID, NAe = (size_t)NA * HID;
  const size_t HH = (size_t)HID * HID;
  char* w = (char*)d_ws;
  size_t off = 0;
  auto alloc = [&](size_t bytes) -> void* {
    void* p = (void*)(w + off);
    off += (bytes + 255) & ~(size_t)255;
    return p;
  };
  bf16* hb_p  = (bf16*)alloc(NPe * 2);
  bf16* hb_a  = (bf16*)alloc(NAe * 2);
  bf16* qkv_p = (bf16*)alloc((size_t)NP * NQP * 2);
  bf16* qkv_a = (bf16*)alloc((size_t)NA * NQA * 2);
  bf16* ag_p  = (bf16*)alloc(NPe * 2);
  bf16* ag_a  = (bf16*)alloc(NAe * 2);
  float* Wf32 = (float*)alloc(12 * HH * 4);
  bf16* WBtP  = (bf16*)alloc((size_t)2 * NQP * HID * 2);
  bf16* WBtA  = (bf16*)alloc((size_t)2 * NQA * HID * 2);
  float* pbP  = (float*)alloc((size_t)2 * NQP * 4);
  float* pbA  = (float*)alloc((size_t)2 * NQA * 4);
  bf16* WaT   = (bf16*)alloc(4 * HH * 2);
  bf16* W256T = (bf16*)alloc((size_t)HID * 256 * 2);
  bf16* W128T = (bf16*)alloc((size_t)256 * 128 * 2);
  bf16* WpTp  = (bf16*)alloc((size_t)INDIM * HID * 2);
  bf16* WpTa  = (bf16*)alloc((size_t)INDIM * HID * 2);
  int* rowptrP = (int*)alloc((size_t)(NP + 1) * 4);
  int* rowptrA = (int*)alloc((size_t)(NA + 1) * 4);
  int* degP    = (int*)alloc((size_t)(2 * NP + 2 * NA) * 4);  // degP|degA|curP|curA
  int* degA    = degP + NP;
  int* curP    = degA + NA;
  int* curA    = curP + NP;
  int* srcsP   = (int*)alloc((size_t)(EC + EW) * 4);
  int* srcsA   = (int*)alloc((size_t)EB * 4);
  int* bsumP   = (int*)alloc(64 * 4);
  int* bsumA   = (int*)alloc(64 * 4);
  if (off > ws_size) return;

  const float scale = 0.08838834764831845f;  // 1/sqrt(128)

  // --- CSR build (merged launches) ---
  (void)hipMemsetAsync(degP, 0, (size_t)(2 * NP + 2 * NA) * 4, stream);
  build_hist3<<<dim3((EC + EW + EB + 255) / 256), 256, 0, stream>>>(ei_c, ei_w, ei_b, degP, degA);
  scan_blk2<<<dim3(NBP + NBA), 256, 0, stream>>>(degP, rowptrP, bsumP, degA, rowptrA, bsumA);
  scan_bsum2<<<dim3(2), 64, 0, stream>>>(bsumP, rowptrP + NP, bsumA, rowptrA + NA);
  scan_add2<<<dim3(NBP + NBA), 256, 0, stream>>>(rowptrP, bsumP, rowptrA, bsumA);
  build_scatter3<<<dim3((EC + EW + EB + 255) / 256), 256, 0, stream>>>(
      ei_c, ei_w, ei_b, rowptrP, curP, srcsP, rowptrA, curA, srcsA);

  // --- fused relation weights + layer packs ---
  FuseArgs fa;
  TrArgs ta;
  CopyB cb;
  for (int l = 0; l < NLAY; l++) {
    bf16* packP = WBtP + (size_t)l * NQP * HID;
    bf16* packA = WBtA + (size_t)l * NQA * HID;
    float* pbPl = pbP + (size_t)l * NQP;
    float* pbAl = pbA + (size_t)l * NQA;
    for (int r = 0; r < 3; r++)
      for (int s = 0; s < 2; s++) {
        int c = (l * 3 + r) * 2 + s;
        int t = (r == 1) ? 1 : 0;
        fa.W[c]   = (s == 0 ? Wk : Wv) + (size_t)(l * 2 + t) * HH;
        fa.rel[c] = (s == 0 ? a_rel : m_rel) + (size_t)(l * 3 + r) * NHEAD * DH * DH;
        fa.bin[c] = (s == 0 ? bk : bv) + (size_t)(l * 2 + t) * HID;
        fa.out[c] = Wf32 + (size_t)c * HH;
        ta.src[c] = fa.out[c];
        if (r == 0) {
          ta.dst[c]  = packP + (size_t)(512 + s * 512) * HID;
          fa.bout[c] = pbPl + 512 + s * 512;
        } else if (r == 1) {
          ta.dst[c]  = packA + (size_t)(512 + s * 512) * HID;
          fa.bout[c] = pbAl + 512 + s * 512;
        } else {
          ta.dst[c]  = packP + (size_t)(1536 + s * 512) * HID;
          fa.bout[c] = pbPl + 1536 + s * 512;
        }
      }
    ta.src[12 + l * 2 + 0] = Wq + (size_t)(l * 2 + 0) * HH;
    ta.dst[12 + l * 2 + 0] = packP;
    ta.src[12 + l * 2 + 1] = Wq + (size_t)(l * 2 + 1) * HH;
    ta.dst[12 + l * 2 + 1] = packA;
    ta.src[16 + l * 2 + 0] = Wa + (size_t)(l * 2 + 0) * HH;
    ta.dst[16 + l * 2 + 0] = WaT + (size_t)(l * 2 + 0) * HH;
    ta.src[16 + l * 2 + 1] = Wa + (size_t)(l * 2 + 1) * HH;
    ta.dst[16 + l * 2 + 1] = WaT + (size_t)(l * 2 + 1) * HH;
    cb.src[l * 2 + 0] = bq + (size_t)(l * 2 + 0) * HID;
    cb.dst[l * 2 + 0] = pbPl;
    cb.src[l * 2 + 1] = bq + (size_t)(l * 2 + 1) * HID;
    cb.dst[l * 2 + 1] = pbAl;
  }
  gemm_fuse<<<dim3(8, 2, 48), 256, 0, stream>>>(fa);
  transpose20<<<dim3(16, 16, 20), dim3(32, 8), 0, stream>>>(ta);
  bias_fuse_all<<<dim3(12), 512, 0, stream>>>(fa);
  copy_bias<<<dim3(4), 512, 0, stream>>>(cb);
  {
    dim3 b(32, 8);
    transpose_to_bf16<<<dim3(8, 16), b, 0, stream>>>(W256, W256T, HID, 256);
    transpose_to_bf16<<<dim3(4, 8), b, 0, stream>>>(W128, W128T, 256, 128);
    transpose_to_bf16<<<dim3(16, 24), b, 0, stream>>>(Wp_paper, WpTp, INDIM, HID);
    transpose_to_bf16<<<dim3(16, 24), b, 0, stream>>>(Wp_author, WpTa, INDIM, HID);
  }

  // --- input conversion + projection ---
  bf16* xb_p = qkv_p;
  bf16* xb_a = qkv_a;
  long long nxp = (long long)NP * INDIM, nxa = (long long)NA * INDIM;
  f32_to_bf16_2<<<dim3((int)(((nxp + nxa) / 4 + 255) / 256)), 256, 0, stream>>>(
      x_paper, xb_p, nxp, x_author, xb_a, nxa);
  {
    GemmPair gp{};
    gp.A0 = xb_p; gp.lda0 = INDIM; gp.B0 = WpTp; gp.ldb0 = INDIM;
    gp.b0 = bp_paper; gp.C0 = hb_p; gp.ldc0 = HID;
    gp.M0 = NP; gp.K0 = INDIM; gp.act0 = 0; gp.bf0 = 1;
    gp.A1 = xb_a; gp.lda1 = INDIM; gp.B1 = WpTa; gp.ldb1 = INDIM;
    gp.b1 = bp_author; gp.C1 = hb_a; gp.ldc1 = HID;
    gp.M1 = NA; gp.K1 = INDIM; gp.act1 = 0; gp.bf1 = 1;
    mgemm2(gp, HID, HID, stream);
  }

  for (int l = 0; l < NLAY; l++) {
    const float* prl = p_rel + (size_t)l * 3 * NHEAD;
    const bf16* packP = WBtP + (size_t)l * NQP * HID;
    const bf16* packA = WBtA + (size_t)l * NQA * HID;
    const float* pbPl = pbP + (size_t)l * NQP;
    const float* pbAl = pbA + (size_t)l * NQA;

    // fused projections pair: q|kv0|kv2 (paper) + q|kv1 (author)
    {
      GemmPair gp{};
      gp.A0 = hb_p; gp.lda0 = HID; gp.B0 = packP; gp.ldb0 = HID;
      gp.b0 = pbPl; gp.C0 = qkv_p; gp.ldc0 = NQP;
      gp.M0 = NP; gp.K0 = HID; gp.act0 = 0; gp.bf0 = 1;
      gp.A1 = hb_a; gp.lda1 = HID; gp.B1 = packA; gp.ldb1 = HID;
      gp.b1 = pbAl; gp.C1 = qkv_a; gp.ldc1 = NQA;
      gp.M1 = NA; gp.K1 = HID; gp.act1 = 0; gp.bf1 = 1;
      mgemm2(gp, NQP, NQA, stream);
    }
    // merged one-pass attention + gelu
    csr_attn_agg2<<<dim3((NP + NA + 3) / 4), 256, 0, stream>>>(
        rowptrP, srcsP, rowptrA, srcsA, qkv_p, qkv_a, prl, scale, ag_p, ag_a);
    // output linear pair (bf16 out into dead qkv slabs)
    bf16* opl_p = qkv_p;
    bf16* opl_a = qkv_a;
    {
      GemmPair gp{};
      gp.A0 = ag_p; gp.lda0 = HID; gp.B0 = WaT + (size_t)(l * 2 + 0) * HH; gp.ldb0 = HID;
      gp.b0 = ba + (size_t)(l * 2 + 0) * HID; gp.C0 = opl_p; gp.ldc0 = HID;
      gp.M0 = NP; gp.K0 = HID; gp.act0 = 0; gp.bf0 = 1;
      gp.A1 = ag_a; gp.lda1 = HID; gp.B1 = WaT + (size_t)(l * 2 + 1) * HH; gp.ldb1 = HID;
      gp.b1 = ba + (size_t)(l * 2 + 1) * HID; gp.C1 = opl_a; gp.ldc1 = HID;
      gp.M1 = NA; gp.K1 = HID; gp.act1 = 0; gp.bf1 = 1;
      mgemm2(gp, HID, HID, stream);
    }
    // merged skip + residual + LN + relu
    skip_ln_relu2<<<dim3(NP + NA), 256, 0, stream>>>(
        opl_p, opl_a, hb_p, hb_a, skip + l * 2,
        ln_g + (size_t)l * HID, ln_b + (size_t)l * HID);
  }

  // final MLP
  bf16* h256_p = ag_p;
  bf16* h256_a = ag_a;
  {
    GemmPair gp{};
    gp.A0 = hb_p; gp.lda0 = HID; gp.B0 = W256T; gp.ldb0 = HID;
    gp.b0 = b256; gp.C0 = h256_p; gp.ldc0 = 256;
    gp.M0 = NP; gp.K0 = HID; gp.act0 = 1; gp.bf0 = 1;
    gp.A1 = hb_a; gp.lda1 = HID; gp.B1 = W256T; gp.ldb1 = HID;
    gp.b1 = b256; gp.C1 = h256_a; gp.ldc1 = 256;
    gp.M1 = NA; gp.K1 = HID; gp.act1 = 1; gp.bf1 = 1;
    mgemm2(gp, 256, 256, stream);
  }
  {
    GemmPair gp{};
    gp.A0 = h256_p; gp.lda0 = 256; gp.B0 = W128T; gp.ldb0 = 256;
    gp.b0 = b128; gp.C0 = out; gp.ldc0 = 128;
    gp.M0 = NP; gp.K0 = 256; gp.act0 = 0; gp.bf0 = 0;
    gp.A1 = h256_a; gp.lda1 = 256; gp.B1 = W128T; gp.ldb1 = 256;
    gp.b1 = b128; gp.C1 = out + (size_t)NP * 128; gp.ldc1 = 128;
    gp.M1 = NA; gp.K1 = 256; gp.act1 = 0; gp.bf1 = 0;
    mgemm2(gp, 128, 128, stream);
  }
}